// Round 24
// baseline (1738.126 us; speedup 1.0000x reference)
//
#include <hip/hip_runtime.h>
#include <math.h>

typedef unsigned short u16;
typedef __attribute__((ext_vector_type(8))) short bf8_t;   // 8 bf16 (4 VGPR)
typedef __attribute__((ext_vector_type(4))) float f4_t;    // 4 fp32

#define BB 256
#define LL 200
#define HH 256
#define EE 512
#define NSTATE 16
#define KCONV 4
#define RR 16
#define NLAYER 2
#define VV 150000
#define TT 300
#define MTOK (BB*TT)      // 76800
#define NC 10             // scan chunks
#define CL 30             // chunk length (10*30 = 300 exactly)
#define XW 1024           // xzb row width (u16): xc 0..511, z 512..1023

#define LOG2E 1.44269504088896340736f
#define LN2   0.69314718055994530942f

// ---------------------------------------------------------------------------
// helpers
// ---------------------------------------------------------------------------
__device__ __forceinline__ float geluf(float x) {
    return 0.5f * x * (1.0f + erff(x * 0.70710678118654752440f));
}
__device__ __forceinline__ u16 f2bf(float x) {               // RNE float->bf16
    unsigned u = __float_as_uint(x);
    unsigned r = u + 0x7FFF + ((u >> 16) & 1);
    return (u16)(r >> 16);
}
__device__ __forceinline__ float bf2f(u16 b) { return __uint_as_float((unsigned)b << 16); }

__device__ __forceinline__ void gload16(const void* gp, void* lp) {
    __builtin_amdgcn_global_load_lds(
        (const __attribute__((address_space(1))) unsigned int*)gp,
        (__attribute__((address_space(3))) unsigned int*)lp,
        16, 0, 0);
}

__device__ __forceinline__ void block_reduce2(float& a, float& b) {
    __shared__ float ra[4], rb[4];
    #pragma unroll
    for (int o = 32; o > 0; o >>= 1) {
        a += __shfl_down(a, o, 64);
        b += __shfl_down(b, o, 64);
    }
    int lane = threadIdx.x & 63, w = threadIdx.x >> 6;
    if (lane == 0) { ra[w] = a; rb[w] = b; }
    __syncthreads();
    a = ra[0] + ra[1] + ra[2] + ra[3];
    b = rb[0] + rb[1] + rb[2] + rb[3];
}

// ---------------------------------------------------------------------------
// split fp32 -> bf16 hi/lo planes (all weights, once per launch)
// ---------------------------------------------------------------------------
__global__ __launch_bounds__(256)
void split_kernel(const float* __restrict__ x, u16* __restrict__ ph,
                  u16* __restrict__ pl, int n) {
    int i = blockIdx.x * 256 + threadIdx.x;
    if (i < n) {
        float v = x[i];
        u16 hb = f2bf(v);
        ph[i] = hb;
        pl[i] = f2bf(v - bf2f(hb));
    }
}

// ---------------------------------------------------------------------------
// 1. embedding gather + LayerNorm -> hi/lo planes of h
// ---------------------------------------------------------------------------
__global__ __launch_bounds__(256)
void embed_ln_kernel(const int* __restrict__ item_seq,
                     const float* __restrict__ item_emb,
                     const float* __restrict__ ln_w,
                     const float* __restrict__ ln_b,
                     u16* __restrict__ hh, u16* __restrict__ hl) {
    int tok = blockIdx.x;
    int b = tok / TT, p = tok - b * TT;
    int k = p / 3, r = p - 3 * k;
    int item;
    if (r == 2) item = VV - 1;
    else        item = item_seq[b * LL + 2 * k + r];
    int tid = threadIdx.x;
    float x = item_emb[(size_t)item * HH + tid];
    float s1 = x, s2 = x * x;
    block_reduce2(s1, s2);
    float m = s1 * (1.0f / HH);
    float var = s2 * (1.0f / HH) - m * m;
    float inv = rsqrtf(var + 1e-12f);
    float v = (x - m) * inv * ln_w[tid] + ln_b[tid];
    size_t idx = (size_t)tok * HH + tid;
    u16 hb = f2bf(v);
    hh[idx] = hb;
    hl[idx] = f2bf(v - bf2f(hb));
}

// ---------------------------------------------------------------------------
// 2. residual add + LayerNorm on the plane residual stream (tmp is bf16)
// ---------------------------------------------------------------------------
__global__ __launch_bounds__(256)
void add_ln_kernel(const u16* __restrict__ tmpb,
                   u16* __restrict__ hh, u16* __restrict__ hl,
                   const float* __restrict__ w,
                   const float* __restrict__ bnorm) {
    int tok = blockIdx.x;
    int tid = threadIdx.x;
    size_t idx = (size_t)tok * HH + tid;
    float x = bf2f(tmpb[idx]) + bf2f(hh[idx]) + bf2f(hl[idx]);
    float s1 = x, s2 = x * x;
    block_reduce2(s1, s2);
    float m = s1 * (1.0f / HH);
    float var = s2 * (1.0f / HH) - m * m;
    float inv = rsqrtf(var + 1e-12f);
    float v = (x - m) * inv * w[tid] + bnorm[tid];
    u16 hb = f2bf(v);
    hh[idx] = hb;
    hl[idx] = f2bf(v - bf2f(hb));
}

// ---------------------------------------------------------------------------
// 3. bf16 MFMA GEMM (128x128 tile, 4 waves, dbuf): C = A @ Wh^T (+bias)
//    1-term: single bf16 A plane x weight-hi.  ldab = A row stride (u16).
//    MODE 2: gelu(C+bias) -> bf16 plane Cb.
//    MODE 3: C (+bias) -> bf16 plane Cb.   Both coalesced via LDS restage.
// ---------------------------------------------------------------------------
template <int MODE>
__global__ __launch_bounds__(256)
void gemm_mfma(const u16* __restrict__ Ah, int ldab,
               const u16* __restrict__ Wh,
               const float* __restrict__ bias,
               u16* __restrict__ Cb,
               int M, int N, int K, int ldc) {
    __shared__ u16 sA[2][128 * 32];       // [buf] 16KB
    __shared__ u16 sB[2][128 * 32];       // [buf] 16KB
    int tid = threadIdx.x;
    int lane = tid & 63, wid = tid >> 6;
    int wr = wid >> 1, wc = wid & 1;

    // XCD-aware bijective swizzle (m204)
    int gx = gridDim.x, nwg = gx * gridDim.y;
    int id = blockIdx.y * gx + blockIdx.x;
    int q = nwg >> 3, rr8 = nwg & 7;
    int xcd = id & 7, pos = id >> 3;
    int nid = (xcd < rr8 ? xcd * (q + 1) : rr8 * (q + 1) + (xcd - rr8) * q) + pos;
    int bn = (nid % gx) * 128;
    int bm = (nid / gx) * 128;

    f4_t acc[4][4];
    #pragma unroll
    for (int i = 0; i < 4; ++i)
        #pragma unroll
        for (int j = 0; j < 4; ++j)
            acc[i][j] = (f4_t){0.f, 0.f, 0.f, 0.f};

    int scol = (lane & 3) * 8;

    auto stageA = [&](int bi, int k0) {
        #pragma unroll
        for (int qq = 0; qq < 2; ++qq) {
            int row = wid * 32 + qq * 16 + (lane >> 2);
            size_t ga = (size_t)(bm + row) * ldab + k0 + scol;
            int off = (wid * 2 + qq) * 1024;
            gload16(Ah + ga, (char*)&sA[bi][0] + off);
        }
    };
    auto stageB = [&](int bi, int k0) {
        #pragma unroll
        for (int qq = 0; qq < 2; ++qq) {
            int row = wid * 32 + qq * 16 + (lane >> 2);
            size_t gb = (size_t)(bn + row) * K + k0 + scol;
            int off = (wid * 2 + qq) * 1024;
            gload16(Wh + gb, (char*)&sB[bi][0] + off);
        }
    };
    auto compute = [&](int bi) {
        int arow = wr * 64 + (lane & 15);
        int koff = (lane >> 4) * 8;
        bf8_t ah[4];
        #pragma unroll
        for (int fm = 0; fm < 4; ++fm) {
            int r = arow + fm * 16;
            ah[fm] = *(const bf8_t*)&sA[bi][r * 32 + koff];
        }
        #pragma unroll
        for (int fn = 0; fn < 4; ++fn) {
            int r = wc * 64 + fn * 16 + (lane & 15);
            bf8_t bh = *(const bf8_t*)&sB[bi][r * 32 + koff];
            #pragma unroll
            for (int fm = 0; fm < 4; ++fm)
                acc[fm][fn] = __builtin_amdgcn_mfma_f32_16x16x32_bf16(ah[fm], bh, acc[fm][fn], 0, 0, 0);
        }
    };

    stageA(0, 0);
    stageB(0, 0);
    __syncthreads();
    int cur = 0;
    for (int k0 = 0; k0 < K; k0 += 32) {
        if (k0 + 32 < K) {
            stageA(cur ^ 1, k0 + 32);
            stageB(cur ^ 1, k0 + 32);
        }
        compute(cur);
        __syncthreads();
        cur ^= 1;
    }

    // epilogue: bf16 plane, coalesced via LDS restage (sA reuse)
    u16* rs = (u16*)&sA[0][0];
    #pragma unroll
    for (int fn = 0; fn < 4; ++fn) {
        int cl = wc * 64 + fn * 16 + (lane & 15);
        float bv = (bias != nullptr) ? bias[bn + cl] : 0.f;
        #pragma unroll
        for (int fm = 0; fm < 4; ++fm) {
            #pragma unroll
            for (int j = 0; j < 4; ++j) {
                int lr = wr * 64 + fm * 16 + (lane >> 4) * 4 + j;
                float v = acc[fm][fn][j] + bv;
                if (MODE == 2) v = geluf(v);
                rs[lr * 128 + cl] = f2bf(v);
            }
        }
    }
    __syncthreads();
    int r = tid >> 1, half = tid & 1;
    u16* dst = Cb + (size_t)(bm + r) * ldc + bn + half * 64;
    const u16* src = rs + r * 128 + half * 64;
    #pragma unroll
    for (int i = 0; i < 8; ++i)
        *(bf8_t*)&dst[i * 8] = *(const bf8_t*)&src[i * 8];
}

// ---------------------------------------------------------------------------
// 3b. narrow x_proj GEMM: xdbl[M,48] = xc @ W[48,512]^T (dbuf)
//     A = bf16 xc plane (row stride XW), W = hi/lo planes.
// ---------------------------------------------------------------------------
__global__ __launch_bounds__(256)
void gemm_xproj(const u16* __restrict__ Axz,           // xzb, row stride XW
                const u16* __restrict__ Wh, const u16* __restrict__ Wl,
                float* __restrict__ C) {               // ldc = 48
    __shared__ u16 sA[2][128 * 32];                    // 16KB
    __shared__ u16 sB[2][2][48 * 32];                  // 12KB
    int tid = threadIdx.x;
    int lane = tid & 63, wid = tid >> 6;
    int bm = blockIdx.x * 128;

    f4_t acc[2][3];
    #pragma unroll
    for (int i = 0; i < 2; ++i)
        #pragma unroll
        for (int j = 0; j < 3; ++j)
            acc[i][j] = (f4_t){0.f, 0.f, 0.f, 0.f};

    int scol = (lane & 3) * 8;

    auto stage = [&](int bi, int k0) {
        #pragma unroll
        for (int qq = 0; qq < 2; ++qq) {
            int row = wid * 32 + qq * 16 + (lane >> 2);
            size_t ga = (size_t)(bm + row) * XW + k0 + scol;
            int off = (wid * 2 + qq) * 1024;
            gload16(Axz + ga, (char*)&sA[bi][0] + off);
        }
        if (tid < 192) {
            int row = tid >> 2;
            int c16 = (tid & 3) * 8;
            size_t gb = (size_t)row * EE + k0 + c16;
            gload16(Wh + gb, (char*)&sB[bi][0][0] + tid * 16);
            gload16(Wl + gb, (char*)&sB[bi][1][0] + tid * 16);
        }
    };
    auto compute = [&](int bi) {
        int arow = wid * 32 + (lane & 15);
        int koff = (lane >> 4) * 8;
        bf8_t ah[2];
        #pragma unroll
        for (int fm = 0; fm < 2; ++fm) {
            int r = arow + fm * 16;
            ah[fm] = *(const bf8_t*)&sA[bi][r * 32 + koff];
        }
        #pragma unroll
        for (int fn = 0; fn < 3; ++fn) {
            int r = fn * 16 + (lane & 15);
            bf8_t bh = *(const bf8_t*)&sB[bi][0][r * 32 + koff];
            bf8_t bl = *(const bf8_t*)&sB[bi][1][r * 32 + koff];
            #pragma unroll
            for (int fm = 0; fm < 2; ++fm) {
                acc[fm][fn] = __builtin_amdgcn_mfma_f32_16x16x32_bf16(ah[fm], bh, acc[fm][fn], 0, 0, 0);
                acc[fm][fn] = __builtin_amdgcn_mfma_f32_16x16x32_bf16(ah[fm], bl, acc[fm][fn], 0, 0, 0);
            }
        }
    };

    stage(0, 0);
    __syncthreads();
    int cur = 0;
    for (int k0 = 0; k0 < EE; k0 += 32) {
        if (k0 + 32 < EE) stage(cur ^ 1, k0 + 32);
        compute(cur);
        __syncthreads();
        cur ^= 1;
    }

    #pragma unroll
    for (int fn = 0; fn < 3; ++fn) {
        int colg = fn * 16 + (lane & 15);
        #pragma unroll
        for (int fm = 0; fm < 2; ++fm) {
            #pragma unroll
            for (int j = 0; j < 4; ++j) {
                int rowg = bm + wid * 32 + fm * 16 + (lane >> 4) * 4 + j;
                C[(size_t)rowg * 48 + colg] = acc[fm][fn][j];
            }
        }
    }
}

// ---------------------------------------------------------------------------
// 4a. conv halo snapshot (reads bf16 xc, stores fp32 halo)
// ---------------------------------------------------------------------------
__global__ __launch_bounds__(256)
void conv_halo_kernel(const u16* __restrict__ xzb, float* __restrict__ halo) {
    int bid = blockIdx.x;
    int ehalf = bid & 1, bc = bid >> 1;
    int c = bc % NC, b = bc / NC;
    int e = ehalf * 256 + threadIdx.x;
    int t0 = c * CL;
    const u16* xp = xzb + (size_t)b * TT * XW + e;
    float* hp = halo + (((size_t)b * NC + c) * 3) * EE + e;
    #pragma unroll
    for (int k = 0; k < 3; ++k) {
        int t = t0 - 3 + k;
        hp[(size_t)k * EE] = (t >= 0) ? bf2f(xp[(size_t)t * XW]) : 0.f;
    }
}

// ---------------------------------------------------------------------------
// 4b. chunked causal depthwise conv (K=4) + bias + SiLU, in place, bf16
// ---------------------------------------------------------------------------
__global__ __launch_bounds__(256)
void conv_chunk_kernel(u16* __restrict__ xzb, const float* __restrict__ halo,
                       const float* __restrict__ conv_w,
                       const float* __restrict__ conv_b, int layer) {
    int bid = blockIdx.x;
    int ehalf = bid & 1, bc = bid >> 1;
    int c = bc % NC, b = bc / NC;
    int e = ehalf * 256 + threadIdx.x;
    int t0 = c * CL;
    const float* w = conv_w + ((size_t)layer * EE + e) * KCONV;
    float w0 = w[0], w1 = w[1], w2 = w[2], w3 = w[3];
    float bias = conv_b[layer * EE + e];
    const float* hp = halo + (((size_t)b * NC + c) * 3) * EE + e;
    float h0 = hp[0], h1 = hp[(size_t)EE], h2 = hp[(size_t)2 * EE];
    u16* p = xzb + ((size_t)b * TT + t0) * XW + e;

    float c0 = bf2f(p[0]);
    float c1 = bf2f(p[(size_t)XW]);
    for (int tg = 0; tg < CL; tg += 2) {
        float n0, n1;
        if (tg + 2 < CL) {
            n0 = bf2f(p[(size_t)(tg + 2) * XW]);
            n1 = bf2f(p[(size_t)(tg + 3) * XW]);
        }
        float v0 = fmaf(w0, h0, fmaf(w1, h1, fmaf(w2, h2, fmaf(w3, c0, bias))));
        float v1 = fmaf(w0, h1, fmaf(w1, h2, fmaf(w2, c0, fmaf(w3, c1, bias))));
        p[(size_t)(tg + 0) * XW] = f2bf(v0 / (1.f + __expf(-v0)));
        p[(size_t)(tg + 1) * XW] = f2bf(v1 / (1.f + __expf(-v1)));
        h0 = h2; h1 = c0; h2 = c1;
        if (tg + 2 < CL) { c0 = n0; c1 = n1; }
    }
}

// ---------------------------------------------------------------------------
// 5. chunked selective scan (NC=10, CL=30), TWO e-values per thread.
//    p1 computes dt (and stores it bf16-packed); p3 READS dt (no dt-proj).
// ---------------------------------------------------------------------------
__device__ __forceinline__ bool chain_check(const float* __restrict__ alp,
                                            float& A0l2e) {
    float a0 = -expf(alp[0]);
    bool ch = true;
    #pragma unroll
    for (int n = 1; n < 16; ++n) {
        float an = -expf(alp[n]);
        ch = ch && (fabsf(an - (n + 1) * a0) <= 1e-3f * (n + 1) * fabsf(a0));
    }
    A0l2e = a0 * LOG2E;
    return ch;
}

template <bool CHAIN, bool EMIT>
__device__ __forceinline__ void scan2_body(
        const float* __restrict__ rowp,
        u16* __restrict__ xp,              // base + e0 (even, 4B aligned)
        u16* __restrict__ dtp,             // dt plane base + e0, stride EE
        const float dw[2][16], const float db[2],
        const float A0[2], const float (*arl)[16],
        const float Dv[2], float2 (*s2)[8], float* dsum) {
    unsigned xcur = *(const unsigned*)xp;
    unsigned zcur = 0;
    if (EMIT) zcur = *(const unsigned*)(xp + EE);
    for (int t = 0; t < CL; ++t) {
        unsigned xnxt = 0, znxt = 0;
        if (t + 1 < CL) {
            xnxt = *(const unsigned*)(xp + (size_t)(t + 1) * XW);
            if (EMIT) znxt = *(const unsigned*)(xp + (size_t)(t + 1) * XW + EE);
        }
        const float* row = rowp + (size_t)t * 48;
        float2 rw[8], Bv[8], Cv[8];
        #pragma unroll
        for (int j = 0; j < 8; ++j) {
            if (!EMIT) rw[j] = *(const float2*)(row + 2 * j);
            Bv[j] = *(const float2*)(row + 16 + 2 * j);
            if (EMIT) Cv[j] = *(const float2*)(row + 32 + 2 * j);
        }
        unsigned dtu = 0;
        if (EMIT) dtu = *(const unsigned*)(dtp + (size_t)t * EE);
        unsigned uout = 0, dtout = 0;
        #pragma unroll
        for (int v = 0; v < 2; ++v) {
            float dt;
            if (!EMIT) {
                float r0 = db[v], r1 = 0.f;
                #pragma unroll
                for (int j = 0; j < 8; ++j) {
                    r0 = fmaf(rw[j].x, dw[v][2 * j], r0);
                    r1 = fmaf(rw[j].y, dw[v][2 * j + 1], r1);
                }
                float rr = r0 + r1;
                float qv = exp2f(-fabsf(rr) * LOG2E);
                float dtf = fmaxf(rr, 0.f) + LN2 * __log2f(1.f + qv);
                u16 dtb16 = f2bf(dtf);
                dtout |= (unsigned)dtb16 << (16 * v);
                dt = bf2f(dtb16);              // rounded, consistent with p3
                dsum[v] += dt;
            } else {
                dt = bf2f((u16)(v == 0 ? (dtu & 0xffffu) : (dtu >> 16)));
            }
            float xv = bf2f((u16)(v == 0 ? (xcur & 0xffffu) : (xcur >> 16)));
            float dx = dt * xv;
            float2 P[8];
            if (CHAIN) {
                float w1 = exp2f(dt * A0[v]);
                float w2 = w1 * w1;
                float2 w2v = make_float2(w2, w2);
                P[0] = make_float2(w1, w2);
                #pragma unroll
                for (int k = 1; k < 8; ++k) P[k] = P[k - 1] * w2v;
            } else {
                #pragma unroll
                for (int k = 0; k < 8; ++k)
                    P[k] = make_float2(exp2f(dt * arl[v][2 * k]),
                                       exp2f(dt * arl[v][2 * k + 1]));
            }
            float2 dx2 = make_float2(dx, dx);
            float2 qa = make_float2(0.f, 0.f), qb = make_float2(0.f, 0.f);
            #pragma unroll
            for (int k = 0; k < 8; ++k) {
                s2[v][k] = s2[v][k] * P[k] + dx2 * Bv[k];
                if (EMIT) {
                    if (k & 1) qb += s2[v][k] * Cv[k];
                    else       qa += s2[v][k] * Cv[k];
                }
            }
            if (EMIT) {
                float2 qs = qa + qb;
                float y = (qs.x + qs.y) + xv * Dv[v];
                float zv = bf2f((u16)(v == 0 ? (zcur & 0xffffu) : (zcur >> 16)));
                float u = y * (zv / (1.f + __expf(-zv)));
                uout |= (unsigned)f2bf(u) << (16 * v);
            }
        }
        if (!EMIT) *(unsigned*)(dtp + (size_t)t * EE) = dtout;
        if (EMIT) *(unsigned*)(xp + (size_t)t * XW) = uout;
        xcur = xnxt; zcur = znxt;
    }
}

__device__ __forceinline__ void load_A_params(
        const float* A_log, int layer, int e0, float A0[2], bool& chain) {
    chain = true;
    #pragma unroll
    for (int v = 0; v < 2; ++v) {
        float a0;
        bool c = chain_check(A_log + ((size_t)layer * EE + e0 + v) * NSTATE, a0);
        A0[v] = a0;
        chain = chain && c;
    }
}

__device__ __forceinline__ void load_arl2(const float* A_log, int layer, int e0,
                                          float arl[2][16]) {
    #pragma unroll
    for (int v = 0; v < 2; ++v) {
        const float* alp = A_log + ((size_t)layer * EE + e0 + v) * NSTATE;
        #pragma unroll
        for (int i = 0; i < 16; i += 4) {
            float4 x4 = *(const float4*)(alp + i);
            arl[v][i + 0] = -expf(x4.x) * LOG2E;
            arl[v][i + 1] = -expf(x4.y) * LOG2E;
            arl[v][i + 2] = -expf(x4.z) * LOG2E;
            arl[v][i + 3] = -expf(x4.w) * LOG2E;
        }
    }
}

__global__ __launch_bounds__(256, 1)
void scan_p1(const float* __restrict__ xdbl, u16* __restrict__ xzb,
             u16* __restrict__ dtb,
             const float* __restrict__ dt_w, const float* __restrict__ dt_b,
             const float* __restrict__ A_log,
             float* __restrict__ SF, float* __restrict__ DS, int layer) {
    int bid = blockIdx.x;
    int c = bid % NC, b = bid / NC;
    int e0 = threadIdx.x * 2;
    int t0 = c * CL;
    float dw[2][16], db[2], A0[2];
    bool chain;
    #pragma unroll
    for (int v = 0; v < 2; ++v) {
        int e = e0 + v;
        #pragma unroll
        for (int i = 0; i < 16; i += 4)
            *(float4*)&dw[v][i] = *(const float4*)(dt_w + ((size_t)layer * EE + e) * RR + i);
        db[v] = dt_b[layer * EE + e];
    }
    load_A_params(A_log, layer, e0, A0, chain);

    const float* rowp = xdbl + ((size_t)b * TT + t0) * 48;
    u16* xp = xzb + ((size_t)b * TT + t0) * XW + e0;
    u16* dtp = dtb + ((size_t)b * TT + t0) * EE + e0;
    float2 s2[2][8];
    #pragma unroll
    for (int v = 0; v < 2; ++v)
        #pragma unroll
        for (int k = 0; k < 8; ++k) s2[v][k] = make_float2(0.f, 0.f);
    float dsum[2] = {0.f, 0.f};
    float Dv[2] = {0.f, 0.f};
    if (chain) {
        scan2_body<true, false>(rowp, xp, dtp, dw, db, A0, nullptr, Dv, s2, dsum);
    } else {
        float arl[2][16];
        load_arl2(A_log, layer, e0, arl);
        scan2_body<false, false>(rowp, xp, dtp, dw, db, A0, arl, Dv, s2, dsum);
    }
    #pragma unroll
    for (int v = 0; v < 2; ++v) {
        size_t sbase = (((size_t)b * EE + e0 + v) * NC + c) * 16;
        #pragma unroll
        for (int k = 0; k < 8; ++k) *(float2*)(SF + sbase + 2 * k) = s2[v][k];
        DS[((size_t)b * EE + e0 + v) * NC + c] = dsum[v];
    }
}

__global__ __launch_bounds__(256)
void scan_p2(const float* __restrict__ A_log,
             float* __restrict__ SF, const float* __restrict__ DS, int layer) {
    int g = blockIdx.x * 256 + threadIdx.x;       // 0..B*E-1
    int e = g & (EE - 1), b = g >> 9;
    const float* alp = A_log + ((size_t)layer * EE + e) * NSTATE;
    float arl2e[16];
    #pragma unroll
    for (int i = 0; i < 16; i += 4) {
        float4 v = *(const float4*)(alp + i);
        arl2e[i + 0] = -expf(v.x) * LOG2E; arl2e[i + 1] = -expf(v.y) * LOG2E;
        arl2e[i + 2] = -expf(v.z) * LOG2E; arl2e[i + 3] = -expf(v.w) * LOG2E;
    }
    float s[16];
    #pragma unroll
    for (int n = 0; n < 16; ++n) s[n] = 0.f;
    size_t base = ((size_t)b * EE + e) * NC;
    for (int c = 0; c < NC; ++c) {
        float ds = DS[base + c];
        alignas(16) float f[16];
        #pragma unroll
        for (int i = 0; i < 16; i += 4) *(float4*)&f[i] = *(const float4*)(SF + (base + c) * 16 + i);
        #pragma unroll
        for (int i = 0; i < 16; i += 4) *(float4*)(SF + (base + c) * 16 + i) = *(float4*)&s[i];
        #pragma unroll
        for (int n = 0; n < 16; ++n) s[n] = fmaf(s[n], exp2f(ds * arl2e[n]), f[n]);
    }
}

__global__ __launch_bounds__(256, 1)
void scan_p3(const float* __restrict__ xdbl, u16* __restrict__ xzb,
             u16* __restrict__ dtb,
             const float* __restrict__ A_log, const float* __restrict__ Dp,
             const float* __restrict__ SF, int layer) {
    int bid = blockIdx.x;
    int c = bid % NC, b = bid / NC;
    int e0 = threadIdx.x * 2;
    int t0 = c * CL;
    float A0[2];
    bool chain;
    load_A_params(A_log, layer, e0, A0, chain);
    float Dv[2];
    Dv[0] = Dp[layer * EE + e0];
    Dv[1] = Dp[layer * EE + e0 + 1];

    const float* rowp = xdbl + ((size_t)b * TT + t0) * 48;
    u16* xp = xzb + ((size_t)b * TT + t0) * XW + e0;
    u16* dtp = dtb + ((size_t)b * TT + t0) * EE + e0;
    float2 s2[2][8];
    #pragma unroll
    for (int v = 0; v < 2; ++v) {
        size_t sbase = (((size_t)b * EE + e0 + v) * NC + c) * 16;
        #pragma unroll
        for (int k = 0; k < 8; ++k) s2[v][k] = *(const float2*)(SF + sbase + 2 * k);
    }
    float dsum[2] = {0.f, 0.f};
    float dwd[2][16];    // unused in EMIT path (compiler prunes)
    float dbd[2] = {0.f, 0.f};
    if (chain) {
        scan2_body<true, true>(rowp, xp, dtp, dwd, dbd, A0, nullptr, Dv, s2, dsum);
    } else {
        float arl[2][16];
        load_arl2(A_log, layer, e0, arl);
        scan2_body<false, true>(rowp, xp, dtp, dwd, dbd, A0, arl, Dv, s2, dsum);
    }
}

// ---------------------------------------------------------------------------
// 6. final gather
// ---------------------------------------------------------------------------
__global__ __launch_bounds__(256)
void gather_out_kernel(const u16* __restrict__ hh, const u16* __restrict__ hl,
                       const int* __restrict__ seq_len,
                       float* __restrict__ out) {
    int b = blockIdx.x;
    int sl = seq_len[b];
    int tl = sl + sl / 2;
    int idx = tl - 1;
    if (idx < 0) idx = 0;
    if (idx > TT - 1) idx = TT - 1;
    size_t src = ((size_t)b * TT + idx) * HH + threadIdx.x;
    out[(size_t)b * HH + threadIdx.x] = bf2f(hh[src]) + bf2f(hl[src]);
}

// ---------------------------------------------------------------------------
// launch
// ---------------------------------------------------------------------------
extern "C" void kernel_launch(void* const* d_in, const int* in_sizes, int n_in,
                              void* d_out, int out_size, void* d_ws, size_t ws_size,
                              hipStream_t stream) {
    const int*   item_seq  = (const int*)  d_in[0];
    const int*   seq_len   = (const int*)  d_in[1];
    const float* item_emb  = (const float*)d_in[2];
    const float* ln_w      = (const float*)d_in[3];
    const float* ln_b      = (const float*)d_in[4];
    const float* in_proj_w = (const float*)d_in[5];
    const float* conv_w    = (const float*)d_in[6];
    const float* conv_b    = (const float*)d_in[7];
    const float* x_proj_w  = (const float*)d_in[8];
    const float* dt_w      = (const float*)d_in[9];
    const float* dt_b      = (const float*)d_in[10];
    const float* A_log     = (const float*)d_in[11];
    const float* Dp        = (const float*)d_in[12];
    const float* out_w     = (const float*)d_in[13];
    const float* mn_w      = (const float*)d_in[14];
    const float* mn_b      = (const float*)d_in[15];
    const float* fc1_w     = (const float*)d_in[16];
    const float* fc1_b     = (const float*)d_in[17];
    const float* fc2_w     = (const float*)d_in[18];
    const float* fc2_b     = (const float*)d_in[19];
    const float* fn_w      = (const float*)d_in[20];
    const float* fn_b      = (const float*)d_in[21];

    // ---- workspace layout: 481.0 MB (< proven 486,604,800 B) ----
    u16*   xzb  = (u16*)d_ws;                         // 157,286,400 B
    u16*   hh   = xzb + (size_t)MTOK * XW;            //  39,321,600 B
    u16*   hl   = hh + (size_t)MTOK * HH;             //  39,321,600 B
    u16*   tmpb = hl + (size_t)MTOK * HH;             //  39,321,600 B
    float* xdbl = (float*)(tmpb + (size_t)MTOK * HH); //  14,745,600 B
    float* SF   = xdbl + (size_t)MTOK * 48;           //  83,886,080 B (B*E*NC*16)
    float* DS   = SF + (size_t)BB * EE * NC * 16;     //   5,242,880 B
    float* halo = DS + (size_t)BB * EE * NC;          //  15,728,640 B (B*NC*3*E)
    u16*   dtb  = (u16*)(halo + (size_t)BB * NC * 3 * EE); // 78,643,200 B
    u16*   pw   = dtb + (size_t)MTOK * EE;            //   7,536,640 B planes
    u16* inH  = pw;                 u16* inL  = inH  + 524288;
    u16* xpH  = inL  + 524288;      u16* xpL  = xpH  + 49152;
    u16* outH = xpL  + 49152;       u16* outL = outH + 262144;
    u16* f1H  = outL + 262144;      u16* f1L  = f1H  + 524288;
    u16* f2H  = f1L  + 524288;      u16* f2L  = f2H  + 524288;
    // fc1 bf16 output plane aliases xzb (xc/z/u dead by then):
    u16* ffb = xzb;

    // ---- split ALL weights once ----
    split_kernel<<<524288 / 256, 256, 0, stream>>>(in_proj_w, inH, inL, 524288);
    split_kernel<<<49152 / 256, 256, 0, stream>>>(x_proj_w, xpH, xpL, 49152);
    split_kernel<<<262144 / 256, 256, 0, stream>>>(out_w, outH, outL, 262144);
    split_kernel<<<524288 / 256, 256, 0, stream>>>(fc1_w, f1H, f1L, 524288);
    split_kernel<<<524288 / 256, 256, 0, stream>>>(fc2_w, f2H, f2L, 524288);

    embed_ln_kernel<<<MTOK, 256, 0, stream>>>(item_seq, item_emb, ln_w, ln_b, hh, hl);

    const int gconv = BB * NC * 2;                    // 5120 blocks
    const int gscan = BB * NC;                        // 2560 blocks (2 e/thread)

    for (int l = 0; l < NLAYER; ++l) {
        // in_proj: xzb = bf16(h @ in_proj_w[l]^T)   (M x 1024, K=256), 1-term
        {
            dim3 grid((2 * EE) / 128, MTOK / 128);
            gemm_mfma<3><<<grid, 256, 0, stream>>>(
                hh, HH,
                inH + (size_t)l * 262144,
                nullptr, xzb, MTOK, 2 * EE, HH, XW);
        }
        // chunked conv (bf16 in place)
        conv_halo_kernel<<<gconv, 256, 0, stream>>>(xzb, halo);
        conv_chunk_kernel<<<gconv, 256, 0, stream>>>(xzb, halo, conv_w, conv_b, l);
        // x_proj (A = bf16 xc plane, W hi/lo)
        gemm_xproj<<<MTOK / 128, 256, 0, stream>>>(
            xzb, xpH + (size_t)l * 24576, xpL + (size_t)l * 24576, xdbl);
        // chunked selective scan (2 e/thread); p1 stores dt; p3 reads dt
        scan_p1<<<gscan, 256, 0, stream>>>(xdbl, xzb, dtb, dt_w, dt_b, A_log, SF, DS, l);
        scan_p2<<<(BB * EE) / 256, 256, 0, stream>>>(A_log, SF, DS, l);
        scan_p3<<<gscan, 256, 0, stream>>>(xdbl, xzb, dtb, A_log, Dp, SF, l);
        // out proj: tmpb = bf16(u @ out_w[l]^T)   (M x 256, K=512), 1-term
        {
            dim3 grid(HH / 128, MTOK / 128);
            gemm_mfma<3><<<grid, 256, 0, stream>>>(
                xzb, XW,
                outH + (size_t)l * 131072,
                nullptr, tmpb, MTOK, HH, EE, HH);
        }
        add_ln_kernel<<<MTOK, 256, 0, stream>>>(tmpb, hh, hl, mn_w + l * HH, mn_b + l * HH);
        // fc1 + GELU -> ffb bf16 plane (alias xzb)  (M x 1024, K=256), 1-term
        {
            dim3 grid((4 * HH) / 128, MTOK / 128);
            gemm_mfma<2><<<grid, 256, 0, stream>>>(
                hh, HH,
                f1H + (size_t)l * 262144,
                fc1_b + (size_t)l * 4 * HH,
                ffb, MTOK, 4 * HH, HH, XW);
        }
        // fc2: tmpb = bf16(ffb @ fc2_w^T + b)   (M x 256, K=1024), 1-term
        {
            dim3 grid(HH / 128, MTOK / 128);
            gemm_mfma<3><<<grid, 256, 0, stream>>>(
                ffb, XW,
                f2H + (size_t)l * 262144,
                fc2_b + (size_t)l * HH,
                tmpb, MTOK, HH, 4 * HH, HH);
        }
        add_ln_kernel<<<MTOK, 256, 0, stream>>>(tmpb, hh, hl, fn_w + l * HH, fn_b + l * HH);
    }

    gather_out_kernel<<<BB, 256, 0, stream>>>(hh, hl, seq_len, (float*)d_out);
}

// Round 25
// 1598.742 us; speedup vs baseline: 1.0872x; 1.0872x over previous
//
#include <hip/hip_runtime.h>
#include <math.h>

typedef unsigned short u16;
typedef __attribute__((ext_vector_type(8))) short bf8_t;   // 8 bf16 (4 VGPR)
typedef __attribute__((ext_vector_type(4))) float f4_t;    // 4 fp32

#define BB 256
#define LL 200
#define HH 256
#define EE 512
#define NSTATE 16
#define KCONV 4
#define RR 16
#define NLAYER 2
#define VV 150000
#define TT 300
#define MTOK (BB*TT)      // 76800
#define NC 6              // scan chunks
#define CL 50             // chunk length (6*50 = 300 exactly)
#define XW 1024           // xzb row width (u16): xc 0..511, z 512..1023

#define LOG2E 1.44269504088896340736f
#define LN2   0.69314718055994530942f

// ---------------------------------------------------------------------------
// helpers
// ---------------------------------------------------------------------------
__device__ __forceinline__ float geluf(float x) {
    return 0.5f * x * (1.0f + erff(x * 0.70710678118654752440f));
}
__device__ __forceinline__ u16 f2bf(float x) {               // RNE float->bf16
    unsigned u = __float_as_uint(x);
    unsigned r = u + 0x7FFF + ((u >> 16) & 1);
    return (u16)(r >> 16);
}
__device__ __forceinline__ float bf2f(u16 b) { return __uint_as_float((unsigned)b << 16); }

__device__ __forceinline__ void gload16(const void* gp, void* lp) {
    __builtin_amdgcn_global_load_lds(
        (const __attribute__((address_space(1))) unsigned int*)gp,
        (__attribute__((address_space(3))) unsigned int*)lp,
        16, 0, 0);
}

__device__ __forceinline__ void block_reduce2(float& a, float& b) {
    __shared__ float ra[4], rb[4];
    #pragma unroll
    for (int o = 32; o > 0; o >>= 1) {
        a += __shfl_down(a, o, 64);
        b += __shfl_down(b, o, 64);
    }
    int lane = threadIdx.x & 63, w = threadIdx.x >> 6;
    if (lane == 0) { ra[w] = a; rb[w] = b; }
    __syncthreads();
    a = ra[0] + ra[1] + ra[2] + ra[3];
    b = rb[0] + rb[1] + rb[2] + rb[3];
}

// ---------------------------------------------------------------------------
// split fp32 -> bf16 hi/lo planes (all weights, once per launch)
// ---------------------------------------------------------------------------
__global__ __launch_bounds__(256)
void split_kernel(const float* __restrict__ x, u16* __restrict__ ph,
                  u16* __restrict__ pl, int n) {
    int i = blockIdx.x * 256 + threadIdx.x;
    if (i < n) {
        float v = x[i];
        u16 hb = f2bf(v);
        ph[i] = hb;
        pl[i] = f2bf(v - bf2f(hb));
    }
}

// ---------------------------------------------------------------------------
// 1. embedding gather + LayerNorm -> hi/lo planes of h
// ---------------------------------------------------------------------------
__global__ __launch_bounds__(256)
void embed_ln_kernel(const int* __restrict__ item_seq,
                     const float* __restrict__ item_emb,
                     const float* __restrict__ ln_w,
                     const float* __restrict__ ln_b,
                     u16* __restrict__ hh, u16* __restrict__ hl) {
    int tok = blockIdx.x;
    int b = tok / TT, p = tok - b * TT;
    int k = p / 3, r = p - 3 * k;
    int item;
    if (r == 2) item = VV - 1;
    else        item = item_seq[b * LL + 2 * k + r];
    int tid = threadIdx.x;
    float x = item_emb[(size_t)item * HH + tid];
    float s1 = x, s2 = x * x;
    block_reduce2(s1, s2);
    float m = s1 * (1.0f / HH);
    float var = s2 * (1.0f / HH) - m * m;
    float inv = rsqrtf(var + 1e-12f);
    float v = (x - m) * inv * ln_w[tid] + ln_b[tid];
    size_t idx = (size_t)tok * HH + tid;
    u16 hb = f2bf(v);
    hh[idx] = hb;
    hl[idx] = f2bf(v - bf2f(hb));
}

// ---------------------------------------------------------------------------
// 2. residual add + LayerNorm on the plane residual stream (tmp is bf16)
// ---------------------------------------------------------------------------
__global__ __launch_bounds__(256)
void add_ln_kernel(const u16* __restrict__ tmpb,
                   u16* __restrict__ hh, u16* __restrict__ hl,
                   const float* __restrict__ w,
                   const float* __restrict__ bnorm) {
    int tok = blockIdx.x;
    int tid = threadIdx.x;
    size_t idx = (size_t)tok * HH + tid;
    float x = bf2f(tmpb[idx]) + bf2f(hh[idx]) + bf2f(hl[idx]);
    float s1 = x, s2 = x * x;
    block_reduce2(s1, s2);
    float m = s1 * (1.0f / HH);
    float var = s2 * (1.0f / HH) - m * m;
    float inv = rsqrtf(var + 1e-12f);
    float v = (x - m) * inv * w[tid] + bnorm[tid];
    u16 hb = f2bf(v);
    hh[idx] = hb;
    hl[idx] = f2bf(v - bf2f(hb));
}

// ---------------------------------------------------------------------------
// 3. bf16 MFMA GEMM (128x128 tile, 4 waves, dbuf): C = A @ Wh^T (+bias)
//    1-term: single bf16 A plane x weight-hi.  ldab = A row stride (u16).
//    MODE 2: gelu(C+bias) -> bf16 plane Cb.
//    MODE 3: C (+bias) -> bf16 plane Cb.   Both coalesced via LDS restage.
// ---------------------------------------------------------------------------
template <int MODE>
__global__ __launch_bounds__(256)
void gemm_mfma(const u16* __restrict__ Ah, int ldab,
               const u16* __restrict__ Wh,
               const float* __restrict__ bias,
               u16* __restrict__ Cb,
               int M, int N, int K, int ldc) {
    __shared__ u16 sA[2][128 * 32];       // [buf] 16KB
    __shared__ u16 sB[2][128 * 32];       // [buf] 16KB
    int tid = threadIdx.x;
    int lane = tid & 63, wid = tid >> 6;
    int wr = wid >> 1, wc = wid & 1;

    // XCD-aware bijective swizzle (m204)
    int gx = gridDim.x, nwg = gx * gridDim.y;
    int id = blockIdx.y * gx + blockIdx.x;
    int q = nwg >> 3, rr8 = nwg & 7;
    int xcd = id & 7, pos = id >> 3;
    int nid = (xcd < rr8 ? xcd * (q + 1) : rr8 * (q + 1) + (xcd - rr8) * q) + pos;
    int bn = (nid % gx) * 128;
    int bm = (nid / gx) * 128;

    f4_t acc[4][4];
    #pragma unroll
    for (int i = 0; i < 4; ++i)
        #pragma unroll
        for (int j = 0; j < 4; ++j)
            acc[i][j] = (f4_t){0.f, 0.f, 0.f, 0.f};

    int scol = (lane & 3) * 8;

    auto stageA = [&](int bi, int k0) {
        #pragma unroll
        for (int qq = 0; qq < 2; ++qq) {
            int row = wid * 32 + qq * 16 + (lane >> 2);
            size_t ga = (size_t)(bm + row) * ldab + k0 + scol;
            int off = (wid * 2 + qq) * 1024;
            gload16(Ah + ga, (char*)&sA[bi][0] + off);
        }
    };
    auto stageB = [&](int bi, int k0) {
        #pragma unroll
        for (int qq = 0; qq < 2; ++qq) {
            int row = wid * 32 + qq * 16 + (lane >> 2);
            size_t gb = (size_t)(bn + row) * K + k0 + scol;
            int off = (wid * 2 + qq) * 1024;
            gload16(Wh + gb, (char*)&sB[bi][0] + off);
        }
    };
    auto compute = [&](int bi) {
        int arow = wr * 64 + (lane & 15);
        int koff = (lane >> 4) * 8;
        bf8_t ah[4];
        #pragma unroll
        for (int fm = 0; fm < 4; ++fm) {
            int r = arow + fm * 16;
            ah[fm] = *(const bf8_t*)&sA[bi][r * 32 + koff];
        }
        #pragma unroll
        for (int fn = 0; fn < 4; ++fn) {
            int r = wc * 64 + fn * 16 + (lane & 15);
            bf8_t bh = *(const bf8_t*)&sB[bi][r * 32 + koff];
            #pragma unroll
            for (int fm = 0; fm < 4; ++fm)
                acc[fm][fn] = __builtin_amdgcn_mfma_f32_16x16x32_bf16(ah[fm], bh, acc[fm][fn], 0, 0, 0);
        }
    };

    stageA(0, 0);
    stageB(0, 0);
    __syncthreads();
    int cur = 0;
    for (int k0 = 0; k0 < K; k0 += 32) {
        if (k0 + 32 < K) {
            stageA(cur ^ 1, k0 + 32);
            stageB(cur ^ 1, k0 + 32);
        }
        compute(cur);
        __syncthreads();
        cur ^= 1;
    }

    // epilogue: bf16 plane, coalesced via LDS restage (sA reuse)
    u16* rs = (u16*)&sA[0][0];
    #pragma unroll
    for (int fn = 0; fn < 4; ++fn) {
        int cl = wc * 64 + fn * 16 + (lane & 15);
        float bv = (bias != nullptr) ? bias[bn + cl] : 0.f;
        #pragma unroll
        for (int fm = 0; fm < 4; ++fm) {
            #pragma unroll
            for (int j = 0; j < 4; ++j) {
                int lr = wr * 64 + fm * 16 + (lane >> 4) * 4 + j;
                float v = acc[fm][fn][j] + bv;
                if (MODE == 2) v = geluf(v);
                rs[lr * 128 + cl] = f2bf(v);
            }
        }
    }
    __syncthreads();
    int r = tid >> 1, half = tid & 1;
    u16* dst = Cb + (size_t)(bm + r) * ldc + bn + half * 64;
    const u16* src = rs + r * 128 + half * 64;
    #pragma unroll
    for (int i = 0; i < 8; ++i)
        *(bf8_t*)&dst[i * 8] = *(const bf8_t*)&src[i * 8];
}

// ---------------------------------------------------------------------------
// 3b. narrow x_proj GEMM: xdbl[M,48] = xc @ W[48,512]^T (dbuf)
//     A = bf16 xc plane (row stride XW), W = hi/lo planes.
// ---------------------------------------------------------------------------
__global__ __launch_bounds__(256)
void gemm_xproj(const u16* __restrict__ Axz,           // xzb, row stride XW
                const u16* __restrict__ Wh, const u16* __restrict__ Wl,
                float* __restrict__ C) {               // ldc = 48
    __shared__ u16 sA[2][128 * 32];                    // 16KB
    __shared__ u16 sB[2][2][48 * 32];                  // 12KB
    int tid = threadIdx.x;
    int lane = tid & 63, wid = tid >> 6;
    int bm = blockIdx.x * 128;

    f4_t acc[2][3];
    #pragma unroll
    for (int i = 0; i < 2; ++i)
        #pragma unroll
        for (int j = 0; j < 3; ++j)
            acc[i][j] = (f4_t){0.f, 0.f, 0.f, 0.f};

    int scol = (lane & 3) * 8;

    auto stage = [&](int bi, int k0) {
        #pragma unroll
        for (int qq = 0; qq < 2; ++qq) {
            int row = wid * 32 + qq * 16 + (lane >> 2);
            size_t ga = (size_t)(bm + row) * XW + k0 + scol;
            int off = (wid * 2 + qq) * 1024;
            gload16(Axz + ga, (char*)&sA[bi][0] + off);
        }
        if (tid < 192) {
            int row = tid >> 2;
            int c16 = (tid & 3) * 8;
            size_t gb = (size_t)row * EE + k0 + c16;
            gload16(Wh + gb, (char*)&sB[bi][0][0] + tid * 16);
            gload16(Wl + gb, (char*)&sB[bi][1][0] + tid * 16);
        }
    };
    auto compute = [&](int bi) {
        int arow = wid * 32 + (lane & 15);
        int koff = (lane >> 4) * 8;
        bf8_t ah[2];
        #pragma unroll
        for (int fm = 0; fm < 2; ++fm) {
            int r = arow + fm * 16;
            ah[fm] = *(const bf8_t*)&sA[bi][r * 32 + koff];
        }
        #pragma unroll
        for (int fn = 0; fn < 3; ++fn) {
            int r = fn * 16 + (lane & 15);
            bf8_t bh = *(const bf8_t*)&sB[bi][0][r * 32 + koff];
            bf8_t bl = *(const bf8_t*)&sB[bi][1][r * 32 + koff];
            #pragma unroll
            for (int fm = 0; fm < 2; ++fm) {
                acc[fm][fn] = __builtin_amdgcn_mfma_f32_16x16x32_bf16(ah[fm], bh, acc[fm][fn], 0, 0, 0);
                acc[fm][fn] = __builtin_amdgcn_mfma_f32_16x16x32_bf16(ah[fm], bl, acc[fm][fn], 0, 0, 0);
            }
        }
    };

    stage(0, 0);
    __syncthreads();
    int cur = 0;
    for (int k0 = 0; k0 < EE; k0 += 32) {
        if (k0 + 32 < EE) stage(cur ^ 1, k0 + 32);
        compute(cur);
        __syncthreads();
        cur ^= 1;
    }

    #pragma unroll
    for (int fn = 0; fn < 3; ++fn) {
        int colg = fn * 16 + (lane & 15);
        #pragma unroll
        for (int fm = 0; fm < 2; ++fm) {
            #pragma unroll
            for (int j = 0; j < 4; ++j) {
                int rowg = bm + wid * 32 + fm * 16 + (lane >> 4) * 4 + j;
                C[(size_t)rowg * 48 + colg] = acc[fm][fn][j];
            }
        }
    }
}

// ---------------------------------------------------------------------------
// 4a. conv halo snapshot (reads bf16 xc, stores fp32 halo)
// ---------------------------------------------------------------------------
__global__ __launch_bounds__(256)
void conv_halo_kernel(const u16* __restrict__ xzb, float* __restrict__ halo) {
    int bid = blockIdx.x;
    int ehalf = bid & 1, bc = bid >> 1;
    int c = bc % NC, b = bc / NC;
    int e = ehalf * 256 + threadIdx.x;
    int t0 = c * CL;
    const u16* xp = xzb + (size_t)b * TT * XW + e;
    float* hp = halo + (((size_t)b * NC + c) * 3) * EE + e;
    #pragma unroll
    for (int k = 0; k < 3; ++k) {
        int t = t0 - 3 + k;
        hp[(size_t)k * EE] = (t >= 0) ? bf2f(xp[(size_t)t * XW]) : 0.f;
    }
}

// ---------------------------------------------------------------------------
// 4b. chunked causal depthwise conv (K=4) + bias + SiLU, in place, bf16
// ---------------------------------------------------------------------------
__global__ __launch_bounds__(256)
void conv_chunk_kernel(u16* __restrict__ xzb, const float* __restrict__ halo,
                       const float* __restrict__ conv_w,
                       const float* __restrict__ conv_b, int layer) {
    int bid = blockIdx.x;
    int ehalf = bid & 1, bc = bid >> 1;
    int c = bc % NC, b = bc / NC;
    int e = ehalf * 256 + threadIdx.x;
    int t0 = c * CL;
    const float* w = conv_w + ((size_t)layer * EE + e) * KCONV;
    float w0 = w[0], w1 = w[1], w2 = w[2], w3 = w[3];
    float bias = conv_b[layer * EE + e];
    const float* hp = halo + (((size_t)b * NC + c) * 3) * EE + e;
    float h0 = hp[0], h1 = hp[(size_t)EE], h2 = hp[(size_t)2 * EE];
    u16* p = xzb + ((size_t)b * TT + t0) * XW + e;

    float c0 = bf2f(p[0]);
    float c1 = bf2f(p[(size_t)XW]);
    for (int tg = 0; tg < CL; tg += 2) {
        float n0, n1;
        if (tg + 2 < CL) {
            n0 = bf2f(p[(size_t)(tg + 2) * XW]);
            n1 = bf2f(p[(size_t)(tg + 3) * XW]);
        }
        float v0 = fmaf(w0, h0, fmaf(w1, h1, fmaf(w2, h2, fmaf(w3, c0, bias))));
        float v1 = fmaf(w0, h1, fmaf(w1, h2, fmaf(w2, c0, fmaf(w3, c1, bias))));
        p[(size_t)(tg + 0) * XW] = f2bf(v0 / (1.f + __expf(-v0)));
        p[(size_t)(tg + 1) * XW] = f2bf(v1 / (1.f + __expf(-v1)));
        h0 = h2; h1 = c0; h2 = c1;
        if (tg + 2 < CL) { c0 = n0; c1 = n1; }
    }
}

// ---------------------------------------------------------------------------
// 5. chunked selective scan (NC=6, CL=50), TWO e-values per thread
//    (e = 2*tid, 2*tid+1): u32 x/z/u accesses, shared row loads, 2x ILP.
// ---------------------------------------------------------------------------
__device__ __forceinline__ bool chain_check(const float* __restrict__ alp,
                                            float& A0l2e) {
    float a0 = -expf(alp[0]);
    bool ch = true;
    #pragma unroll
    for (int n = 1; n < 16; ++n) {
        float an = -expf(alp[n]);
        ch = ch && (fabsf(an - (n + 1) * a0) <= 1e-3f * (n + 1) * fabsf(a0));
    }
    A0l2e = a0 * LOG2E;
    return ch;
}

template <bool CHAIN, bool EMIT>
__device__ __forceinline__ void scan2_body(
        const float* __restrict__ rowp,
        u16* __restrict__ xp,              // base + e0 (even, 4B aligned)
        const float dw[2][16], const float db[2],
        const float A0[2], const float (*arl)[16],
        const float Dv[2], float2 (*s2)[8], float* dsum) {
    unsigned xcur = *(const unsigned*)xp;
    unsigned zcur = 0;
    if (EMIT) zcur = *(const unsigned*)(xp + EE);
    for (int t = 0; t < CL; ++t) {
        unsigned xnxt = 0, znxt = 0;
        if (t + 1 < CL) {
            xnxt = *(const unsigned*)(xp + (size_t)(t + 1) * XW);
            if (EMIT) znxt = *(const unsigned*)(xp + (size_t)(t + 1) * XW + EE);
        }
        const float* row = rowp + (size_t)t * 48;
        float2 rw[8], Bv[8], Cv[8];
        #pragma unroll
        for (int j = 0; j < 8; ++j) {
            rw[j] = *(const float2*)(row + 2 * j);
            Bv[j] = *(const float2*)(row + 16 + 2 * j);
            if (EMIT) Cv[j] = *(const float2*)(row + 32 + 2 * j);
        }
        unsigned uout = 0;
        #pragma unroll
        for (int v = 0; v < 2; ++v) {
            float r0 = db[v], r1 = 0.f;
            #pragma unroll
            for (int j = 0; j < 8; ++j) {
                r0 = fmaf(rw[j].x, dw[v][2 * j], r0);
                r1 = fmaf(rw[j].y, dw[v][2 * j + 1], r1);
            }
            float rr = r0 + r1;
            float qv = exp2f(-fabsf(rr) * LOG2E);
            float dt = fmaxf(rr, 0.f) + LN2 * __log2f(1.f + qv);
            if (!EMIT) dsum[v] += dt;
            float xv = bf2f((u16)(v == 0 ? (xcur & 0xffffu) : (xcur >> 16)));
            float dx = dt * xv;
            float2 P[8];
            if (CHAIN) {
                float w1 = exp2f(dt * A0[v]);
                float w2 = w1 * w1;
                float2 w2v = make_float2(w2, w2);
                P[0] = make_float2(w1, w2);
                #pragma unroll
                for (int k = 1; k < 8; ++k) P[k] = P[k - 1] * w2v;
            } else {
                #pragma unroll
                for (int k = 0; k < 8; ++k)
                    P[k] = make_float2(exp2f(dt * arl[v][2 * k]),
                                       exp2f(dt * arl[v][2 * k + 1]));
            }
            float2 dx2 = make_float2(dx, dx);
            float2 qa = make_float2(0.f, 0.f), qb = make_float2(0.f, 0.f);
            #pragma unroll
            for (int k = 0; k < 8; ++k) {
                s2[v][k] = s2[v][k] * P[k] + dx2 * Bv[k];
                if (EMIT) {
                    if (k & 1) qb += s2[v][k] * Cv[k];
                    else       qa += s2[v][k] * Cv[k];
                }
            }
            if (EMIT) {
                float2 qs = qa + qb;
                float y = (qs.x + qs.y) + xv * Dv[v];
                float zv = bf2f((u16)(v == 0 ? (zcur & 0xffffu) : (zcur >> 16)));
                float u = y * (zv / (1.f + __expf(-zv)));
                uout |= (unsigned)f2bf(u) << (16 * v);
            }
        }
        if (EMIT) *(unsigned*)(xp + (size_t)t * XW) = uout;
        xcur = xnxt; zcur = znxt;
    }
}

__device__ __forceinline__ void load_scan2_params(
        const float* dt_w, const float* dt_b, const float* A_log,
        int layer, int e0, float dw[2][16], float db[2], float A0[2],
        bool& chain) {
    chain = true;
    #pragma unroll
    for (int v = 0; v < 2; ++v) {
        int e = e0 + v;
        #pragma unroll
        for (int i = 0; i < 16; i += 4)
            *(float4*)&dw[v][i] = *(const float4*)(dt_w + ((size_t)layer * EE + e) * RR + i);
        db[v] = dt_b[layer * EE + e];
        float a0;
        bool c = chain_check(A_log + ((size_t)layer * EE + e) * NSTATE, a0);
        A0[v] = a0;
        chain = chain && c;
    }
}

__device__ __forceinline__ void load_arl2(const float* A_log, int layer, int e0,
                                          float arl[2][16]) {
    #pragma unroll
    for (int v = 0; v < 2; ++v) {
        const float* alp = A_log + ((size_t)layer * EE + e0 + v) * NSTATE;
        #pragma unroll
        for (int i = 0; i < 16; i += 4) {
            float4 x4 = *(const float4*)(alp + i);
            arl[v][i + 0] = -expf(x4.x) * LOG2E;
            arl[v][i + 1] = -expf(x4.y) * LOG2E;
            arl[v][i + 2] = -expf(x4.z) * LOG2E;
            arl[v][i + 3] = -expf(x4.w) * LOG2E;
        }
    }
}

__global__ __launch_bounds__(256, 1)
void scan_p1(const float* __restrict__ xdbl, u16* __restrict__ xzb,
             const float* __restrict__ dt_w, const float* __restrict__ dt_b,
             const float* __restrict__ A_log,
             float* __restrict__ SF, float* __restrict__ DS, int layer) {
    int bid = blockIdx.x;
    int c = bid % NC, b = bid / NC;
    int e0 = threadIdx.x * 2;
    int t0 = c * CL;
    float dw[2][16], db[2], A0[2];
    bool chain;
    load_scan2_params(dt_w, dt_b, A_log, layer, e0, dw, db, A0, chain);

    const float* rowp = xdbl + ((size_t)b * TT + t0) * 48;
    u16* xp = xzb + ((size_t)b * TT + t0) * XW + e0;
    float2 s2[2][8];
    #pragma unroll
    for (int v = 0; v < 2; ++v)
        #pragma unroll
        for (int k = 0; k < 8; ++k) s2[v][k] = make_float2(0.f, 0.f);
    float dsum[2] = {0.f, 0.f};
    float Dv[2] = {0.f, 0.f};
    if (chain) {
        scan2_body<true, false>(rowp, xp, dw, db, A0, nullptr, Dv, s2, dsum);
    } else {
        float arl[2][16];
        load_arl2(A_log, layer, e0, arl);
        scan2_body<false, false>(rowp, xp, dw, db, A0, arl, Dv, s2, dsum);
    }
    #pragma unroll
    for (int v = 0; v < 2; ++v) {
        size_t sbase = (((size_t)b * EE + e0 + v) * NC + c) * 16;
        #pragma unroll
        for (int k = 0; k < 8; ++k) *(float2*)(SF + sbase + 2 * k) = s2[v][k];
        DS[((size_t)b * EE + e0 + v) * NC + c] = dsum[v];
    }
}

__global__ __launch_bounds__(256)
void scan_p2(const float* __restrict__ A_log,
             float* __restrict__ SF, const float* __restrict__ DS, int layer) {
    int g = blockIdx.x * 256 + threadIdx.x;       // 0..B*E-1
    int e = g & (EE - 1), b = g >> 9;
    const float* alp = A_log + ((size_t)layer * EE + e) * NSTATE;
    float arl2e[16];
    #pragma unroll
    for (int i = 0; i < 16; i += 4) {
        float4 v = *(const float4*)(alp + i);
        arl2e[i + 0] = -expf(v.x) * LOG2E; arl2e[i + 1] = -expf(v.y) * LOG2E;
        arl2e[i + 2] = -expf(v.z) * LOG2E; arl2e[i + 3] = -expf(v.w) * LOG2E;
    }
    float s[16];
    #pragma unroll
    for (int n = 0; n < 16; ++n) s[n] = 0.f;
    size_t base = ((size_t)b * EE + e) * NC;
    for (int c = 0; c < NC; ++c) {
        float ds = DS[base + c];
        alignas(16) float f[16];
        #pragma unroll
        for (int i = 0; i < 16; i += 4) *(float4*)&f[i] = *(const float4*)(SF + (base + c) * 16 + i);
        #pragma unroll
        for (int i = 0; i < 16; i += 4) *(float4*)(SF + (base + c) * 16 + i) = *(float4*)&s[i];
        #pragma unroll
        for (int n = 0; n < 16; ++n) s[n] = fmaf(s[n], exp2f(ds * arl2e[n]), f[n]);
    }
}

__global__ __launch_bounds__(256, 1)
void scan_p3(const float* __restrict__ xdbl, u16* __restrict__ xzb,
             const float* __restrict__ dt_w, const float* __restrict__ dt_b,
             const float* __restrict__ A_log, const float* __restrict__ Dp,
             const float* __restrict__ SF, int layer) {
    int bid = blockIdx.x;
    int c = bid % NC, b = bid / NC;
    int e0 = threadIdx.x * 2;
    int t0 = c * CL;
    float dw[2][16], db[2], A0[2];
    bool chain;
    load_scan2_params(dt_w, dt_b, A_log, layer, e0, dw, db, A0, chain);
    float Dv[2];
    Dv[0] = Dp[layer * EE + e0];
    Dv[1] = Dp[layer * EE + e0 + 1];

    const float* rowp = xdbl + ((size_t)b * TT + t0) * 48;
    u16* xp = xzb + ((size_t)b * TT + t0) * XW + e0;
    float2 s2[2][8];
    #pragma unroll
    for (int v = 0; v < 2; ++v) {
        size_t sbase = (((size_t)b * EE + e0 + v) * NC + c) * 16;
        #pragma unroll
        for (int k = 0; k < 8; ++k) s2[v][k] = *(const float2*)(SF + sbase + 2 * k);
    }
    float dsum[2] = {0.f, 0.f};
    if (chain) {
        scan2_body<true, true>(rowp, xp, dw, db, A0, nullptr, Dv, s2, dsum);
    } else {
        float arl[2][16];
        load_arl2(A_log, layer, e0, arl);
        scan2_body<false, true>(rowp, xp, dw, db, A0, arl, Dv, s2, dsum);
    }
}

// ---------------------------------------------------------------------------
// 6. final gather
// ---------------------------------------------------------------------------
__global__ __launch_bounds__(256)
void gather_out_kernel(const u16* __restrict__ hh, const u16* __restrict__ hl,
                       const int* __restrict__ seq_len,
                       float* __restrict__ out) {
    int b = blockIdx.x;
    int sl = seq_len[b];
    int tl = sl + sl / 2;
    int idx = tl - 1;
    if (idx < 0) idx = 0;
    if (idx > TT - 1) idx = TT - 1;
    size_t src = ((size_t)b * TT + idx) * HH + threadIdx.x;
    out[(size_t)b * HH + threadIdx.x] = bf2f(hh[src]) + bf2f(hl[src]);
}

// ---------------------------------------------------------------------------
// launch
// ---------------------------------------------------------------------------
extern "C" void kernel_launch(void* const* d_in, const int* in_sizes, int n_in,
                              void* d_out, int out_size, void* d_ws, size_t ws_size,
                              hipStream_t stream) {
    const int*   item_seq  = (const int*)  d_in[0];
    const int*   seq_len   = (const int*)  d_in[1];
    const float* item_emb  = (const float*)d_in[2];
    const float* ln_w      = (const float*)d_in[3];
    const float* ln_b      = (const float*)d_in[4];
    const float* in_proj_w = (const float*)d_in[5];
    const float* conv_w    = (const float*)d_in[6];
    const float* conv_b    = (const float*)d_in[7];
    const float* x_proj_w  = (const float*)d_in[8];
    const float* dt_w      = (const float*)d_in[9];
    const float* dt_b      = (const float*)d_in[10];
    const float* A_log     = (const float*)d_in[11];
    const float* Dp        = (const float*)d_in[12];
    const float* out_w     = (const float*)d_in[13];
    const float* mn_w      = (const float*)d_in[14];
    const float* mn_b      = (const float*)d_in[15];
    const float* fc1_w     = (const float*)d_in[16];
    const float* fc1_b     = (const float*)d_in[17];
    const float* fc2_w     = (const float*)d_in[18];
    const float* fc2_b     = (const float*)d_in[19];
    const float* fn_w      = (const float*)d_in[20];
    const float* fn_b      = (const float*)d_in[21];

    // ---- workspace layout (~360 MB, well under proven 486 MB) ----
    u16*   xzb  = (u16*)d_ws;                         // 157,286,400 B
    u16*   hh   = xzb + (size_t)MTOK * XW;            //  39,321,600 B
    u16*   hl   = hh + (size_t)MTOK * HH;             //  39,321,600 B
    u16*   tmpb = hl + (size_t)MTOK * HH;             //  39,321,600 B
    float* xdbl = (float*)(tmpb + (size_t)MTOK * HH); //  14,745,600 B
    float* SF   = xdbl + (size_t)MTOK * 48;           //  50,331,648 B (B*E*NC*16)
    float* DS   = SF + (size_t)BB * EE * NC * 16;     //   3,145,728 B
    float* halo = DS + (size_t)BB * EE * NC;          //   9,437,184 B (B*NC*3*E)
    u16*   pw   = (u16*)(halo + (size_t)BB * NC * 3 * EE); // 7,536,640 B planes
    u16* inH  = pw;                 u16* inL  = inH  + 524288;
    u16* xpH  = inL  + 524288;      u16* xpL  = xpH  + 49152;
    u16* outH = xpL  + 49152;       u16* outL = outH + 262144;
    u16* f1H  = outL + 262144;      u16* f1L  = f1H  + 524288;
    u16* f2H  = f1L  + 524288;      u16* f2L  = f2H  + 524288;
    // fc1 bf16 output plane aliases xzb (xc/z/u dead by then):
    u16* ffb = xzb;

    // ---- split ALL weights once ----
    split_kernel<<<524288 / 256, 256, 0, stream>>>(in_proj_w, inH, inL, 524288);
    split_kernel<<<49152 / 256, 256, 0, stream>>>(x_proj_w, xpH, xpL, 49152);
    split_kernel<<<262144 / 256, 256, 0, stream>>>(out_w, outH, outL, 262144);
    split_kernel<<<524288 / 256, 256, 0, stream>>>(fc1_w, f1H, f1L, 524288);
    split_kernel<<<524288 / 256, 256, 0, stream>>>(fc2_w, f2H, f2L, 524288);

    embed_ln_kernel<<<MTOK, 256, 0, stream>>>(item_seq, item_emb, ln_w, ln_b, hh, hl);

    const int gconv = BB * NC * 2;                    // 3072 blocks
    const int gscan = BB * NC;                        // 1536 blocks (2 e/thread)

    for (int l = 0; l < NLAYER; ++l) {
        // in_proj: xzb = bf16(h @ in_proj_w[l]^T)   (M x 1024, K=256), 1-term
        {
            dim3 grid((2 * EE) / 128, MTOK / 128);
            gemm_mfma<3><<<grid, 256, 0, stream>>>(
                hh, HH,
                inH + (size_t)l * 262144,
                nullptr, xzb, MTOK, 2 * EE, HH, XW);
        }
        // chunked conv (bf16 in place)
        conv_halo_kernel<<<gconv, 256, 0, stream>>>(xzb, halo);
        conv_chunk_kernel<<<gconv, 256, 0, stream>>>(xzb, halo, conv_w, conv_b, l);
        // x_proj (A = bf16 xc plane, W hi/lo)
        gemm_xproj<<<MTOK / 128, 256, 0, stream>>>(
            xzb, xpH + (size_t)l * 24576, xpL + (size_t)l * 24576, xdbl);
        // chunked selective scan (2 e/thread); p3 writes u bf16 over xc slots
        scan_p1<<<gscan, 256, 0, stream>>>(xdbl, xzb, dt_w, dt_b, A_log, SF, DS, l);
        scan_p2<<<(BB * EE) / 256, 256, 0, stream>>>(A_log, SF, DS, l);
        scan_p3<<<gscan, 256, 0, stream>>>(xdbl, xzb, dt_w, dt_b, A_log, Dp, SF, l);
        // out proj: tmpb = bf16(u @ out_w[l]^T)   (M x 256, K=512), 1-term
        {
            dim3 grid(HH / 128, MTOK / 128);
            gemm_mfma<3><<<grid, 256, 0, stream>>>(
                xzb, XW,
                outH + (size_t)l * 131072,
                nullptr, tmpb, MTOK, HH, EE, HH);
        }
        add_ln_kernel<<<MTOK, 256, 0, stream>>>(tmpb, hh, hl, mn_w + l * HH, mn_b + l * HH);
        // fc1 + GELU -> ffb bf16 plane (alias xzb)  (M x 1024, K=256), 1-term
        {
            dim3 grid((4 * HH) / 128, MTOK / 128);
            gemm_mfma<2><<<grid, 256, 0, stream>>>(
                hh, HH,
                f1H + (size_t)l * 262144,
                fc1_b + (size_t)l * 4 * HH,
                ffb, MTOK, 4 * HH, HH, XW);
        }
        // fc2: tmpb = bf16(ffb @ fc2_w^T + b)   (M x 256, K=1024), 1-term
        {
            dim3 grid(HH / 128, MTOK / 128);
            gemm_mfma<3><<<grid, 256, 0, stream>>>(
                ffb, XW,
                f2H + (size_t)l * 262144,
                fc2_b + (size_t)l * HH,
                tmpb, MTOK, HH, 4 * HH, HH);
        }
        add_ln_kernel<<<MTOK, 256, 0, stream>>>(tmpb, hh, hl, fn_w + l * HH, fn_b + l * HH);
    }

    gather_out_kernel<<<BB, 256, 0, stream>>>(hh, hl, seq_len, (float*)d_out);
}

// Round 26
// 1416.473 us; speedup vs baseline: 1.2271x; 1.1287x over previous
//
#include <hip/hip_runtime.h>
#include <math.h>

typedef unsigned short u16;
typedef __attribute__((ext_vector_type(8))) short bf8_t;   // 8 bf16 (4 VGPR)
typedef __attribute__((ext_vector_type(4))) float f4_t;    // 4 fp32
typedef __attribute__((ext_vector_type(4))) unsigned short u16x4;

#define BB 256
#define LL 200
#define HH 256
#define EE 512
#define NSTATE 16
#define KCONV 4
#define RR 16
#define NLAYER 2
#define VV 150000
#define TT 300
#define MTOK (BB*TT)      // 76800
#define NC 6              // scan chunks
#define CL 50             // chunk length (6*50 = 300 exactly)
#define XW 1024           // xzb row width (u16): xc 0..511, z 512..1023

#define LOG2E 1.44269504088896340736f
#define LN2   0.69314718055994530942f

// ---------------------------------------------------------------------------
// helpers
// ---------------------------------------------------------------------------
__device__ __forceinline__ float geluf(float x) {
    return 0.5f * x * (1.0f + erff(x * 0.70710678118654752440f));
}
__device__ __forceinline__ u16 f2bf(float x) {               // RNE float->bf16
    unsigned u = __float_as_uint(x);
    unsigned r = u + 0x7FFF + ((u >> 16) & 1);
    return (u16)(r >> 16);
}
__device__ __forceinline__ float bf2f(u16 b) { return __uint_as_float((unsigned)b << 16); }

__device__ __forceinline__ void gload16(const void* gp, void* lp) {
    __builtin_amdgcn_global_load_lds(
        (const __attribute__((address_space(1))) unsigned int*)gp,
        (__attribute__((address_space(3))) unsigned int*)lp,
        16, 0, 0);
}

// ---------------------------------------------------------------------------
// split fp32 -> bf16 hi/lo planes (all weights, once per launch)
// ---------------------------------------------------------------------------
__global__ __launch_bounds__(256)
void split_kernel(const float* __restrict__ x, u16* __restrict__ ph,
                  u16* __restrict__ pl, int n) {
    int i = blockIdx.x * 256 + threadIdx.x;
    if (i < n) {
        float v = x[i];
        u16 hb = f2bf(v);
        ph[i] = hb;
        pl[i] = f2bf(v - bf2f(hb));
    }
}

// ---------------------------------------------------------------------------
// 1. embedding gather + LayerNorm -> hi/lo planes of h
//    Wave-per-token: 4 tokens/block, 4 elems/lane, shuffle-only reduce.
// ---------------------------------------------------------------------------
__global__ __launch_bounds__(256)
void embed_ln_kernel(const int* __restrict__ item_seq,
                     const float* __restrict__ item_emb,
                     const float* __restrict__ ln_w,
                     const float* __restrict__ ln_b,
                     u16* __restrict__ hh, u16* __restrict__ hl) {
    int wid = threadIdx.x >> 6, lane = threadIdx.x & 63;
    int tok = blockIdx.x * 4 + wid;
    int b = tok / TT, p = tok - b * TT;
    int k = p / 3, r = p - 3 * k;
    int item = (r == 2) ? (VV - 1) : item_seq[b * LL + 2 * k + r];
    float4 x4 = *(const float4*)&item_emb[(size_t)item * HH + lane * 4];
    float x[4] = {x4.x, x4.y, x4.z, x4.w};
    float s1 = x[0] + x[1] + x[2] + x[3];
    float s2 = x[0]*x[0] + x[1]*x[1] + x[2]*x[2] + x[3]*x[3];
    #pragma unroll
    for (int o = 32; o > 0; o >>= 1) {
        s1 += __shfl_xor(s1, o, 64);
        s2 += __shfl_xor(s2, o, 64);
    }
    float m = s1 * (1.0f / HH);
    float var = s2 * (1.0f / HH) - m * m;
    float inv = rsqrtf(var + 1e-12f);
    float4 w4 = *(const float4*)&ln_w[lane * 4];
    float4 b4 = *(const float4*)&ln_b[lane * 4];
    float wv[4] = {w4.x, w4.y, w4.z, w4.w};
    float bv[4] = {b4.x, b4.y, b4.z, b4.w};
    u16x4 ho, lo;
    #pragma unroll
    for (int j = 0; j < 4; ++j) {
        float v = (x[j] - m) * inv * wv[j] + bv[j];
        u16 hb = f2bf(v);
        ho[j] = hb;
        lo[j] = f2bf(v - bf2f(hb));
    }
    size_t idx = (size_t)tok * HH + lane * 4;
    *(u16x4*)&hh[idx] = ho;
    *(u16x4*)&hl[idx] = lo;
}

// ---------------------------------------------------------------------------
// 2. residual add + LayerNorm (tmp bf16), wave-per-token
// ---------------------------------------------------------------------------
__global__ __launch_bounds__(256)
void add_ln_kernel(const u16* __restrict__ tmpb,
                   u16* __restrict__ hh, u16* __restrict__ hl,
                   const float* __restrict__ w,
                   const float* __restrict__ bnorm) {
    int wid = threadIdx.x >> 6, lane = threadIdx.x & 63;
    int tok = blockIdx.x * 4 + wid;
    size_t idx = (size_t)tok * HH + lane * 4;
    u16x4 tv = *(const u16x4*)&tmpb[idx];
    u16x4 hv = *(const u16x4*)&hh[idx];
    u16x4 lv = *(const u16x4*)&hl[idx];
    float x[4];
    #pragma unroll
    for (int j = 0; j < 4; ++j)
        x[j] = bf2f(tv[j]) + bf2f(hv[j]) + bf2f(lv[j]);
    float s1 = x[0] + x[1] + x[2] + x[3];
    float s2 = x[0]*x[0] + x[1]*x[1] + x[2]*x[2] + x[3]*x[3];
    #pragma unroll
    for (int o = 32; o > 0; o >>= 1) {
        s1 += __shfl_xor(s1, o, 64);
        s2 += __shfl_xor(s2, o, 64);
    }
    float m = s1 * (1.0f / HH);
    float var = s2 * (1.0f / HH) - m * m;
    float inv = rsqrtf(var + 1e-12f);
    float4 w4 = *(const float4*)&w[lane * 4];
    float4 b4 = *(const float4*)&bnorm[lane * 4];
    float wv[4] = {w4.x, w4.y, w4.z, w4.w};
    float bv[4] = {b4.x, b4.y, b4.z, b4.w};
    u16x4 ho, lo;
    #pragma unroll
    for (int j = 0; j < 4; ++j) {
        float v = (x[j] - m) * inv * wv[j] + bv[j];
        u16 hb = f2bf(v);
        ho[j] = hb;
        lo[j] = f2bf(v - bf2f(hb));
    }
    *(u16x4*)&hh[idx] = ho;
    *(u16x4*)&hl[idx] = lo;
}

// ---------------------------------------------------------------------------
// 3. bf16 MFMA GEMM (128x128 tile, 4 waves, dbuf): C = A @ Wh^T (+bias)
//    1-term: single bf16 A plane x weight-hi.  ldab = A row stride (u16).
//    MODE 2: gelu(C+bias) -> bf16 plane Cb.
//    MODE 3: C (+bias) -> bf16 plane Cb.
//    MODE 4: C -> bf16 plane, silu applied to cols >= 512 (z half, in_proj).
//    All coalesced via LDS restage.
// ---------------------------------------------------------------------------
template <int MODE>
__global__ __launch_bounds__(256)
void gemm_mfma(const u16* __restrict__ Ah, int ldab,
               const u16* __restrict__ Wh,
               const float* __restrict__ bias,
               u16* __restrict__ Cb,
               int M, int N, int K, int ldc) {
    __shared__ u16 sA[2][128 * 32];       // [buf] 16KB
    __shared__ u16 sB[2][128 * 32];       // [buf] 16KB
    int tid = threadIdx.x;
    int lane = tid & 63, wid = tid >> 6;
    int wr = wid >> 1, wc = wid & 1;

    // XCD-aware bijective swizzle (m204)
    int gx = gridDim.x, nwg = gx * gridDim.y;
    int id = blockIdx.y * gx + blockIdx.x;
    int q = nwg >> 3, rr8 = nwg & 7;
    int xcd = id & 7, pos = id >> 3;
    int nid = (xcd < rr8 ? xcd * (q + 1) : rr8 * (q + 1) + (xcd - rr8) * q) + pos;
    int bn = (nid % gx) * 128;
    int bm = (nid / gx) * 128;

    f4_t acc[4][4];
    #pragma unroll
    for (int i = 0; i < 4; ++i)
        #pragma unroll
        for (int j = 0; j < 4; ++j)
            acc[i][j] = (f4_t){0.f, 0.f, 0.f, 0.f};

    int scol = (lane & 3) * 8;

    auto stageA = [&](int bi, int k0) {
        #pragma unroll
        for (int qq = 0; qq < 2; ++qq) {
            int row = wid * 32 + qq * 16 + (lane >> 2);
            size_t ga = (size_t)(bm + row) * ldab + k0 + scol;
            int off = (wid * 2 + qq) * 1024;
            gload16(Ah + ga, (char*)&sA[bi][0] + off);
        }
    };
    auto stageB = [&](int bi, int k0) {
        #pragma unroll
        for (int qq = 0; qq < 2; ++qq) {
            int row = wid * 32 + qq * 16 + (lane >> 2);
            size_t gb = (size_t)(bn + row) * K + k0 + scol;
            int off = (wid * 2 + qq) * 1024;
            gload16(Wh + gb, (char*)&sB[bi][0] + off);
        }
    };
    auto compute = [&](int bi) {
        int arow = wr * 64 + (lane & 15);
        int koff = (lane >> 4) * 8;
        bf8_t ah[4];
        #pragma unroll
        for (int fm = 0; fm < 4; ++fm) {
            int r = arow + fm * 16;
            ah[fm] = *(const bf8_t*)&sA[bi][r * 32 + koff];
        }
        #pragma unroll
        for (int fn = 0; fn < 4; ++fn) {
            int r = wc * 64 + fn * 16 + (lane & 15);
            bf8_t bh = *(const bf8_t*)&sB[bi][r * 32 + koff];
            #pragma unroll
            for (int fm = 0; fm < 4; ++fm)
                acc[fm][fn] = __builtin_amdgcn_mfma_f32_16x16x32_bf16(ah[fm], bh, acc[fm][fn], 0, 0, 0);
        }
    };

    stageA(0, 0);
    stageB(0, 0);
    __syncthreads();
    int cur = 0;
    for (int k0 = 0; k0 < K; k0 += 32) {
        if (k0 + 32 < K) {
            stageA(cur ^ 1, k0 + 32);
            stageB(cur ^ 1, k0 + 32);
        }
        compute(cur);
        __syncthreads();
        cur ^= 1;
    }

    // epilogue: bf16 plane, coalesced via LDS restage (sA reuse)
    u16* rs = (u16*)&sA[0][0];
    bool zhalf = (MODE == 4) && (bn >= 512);       // block-uniform
    #pragma unroll
    for (int fn = 0; fn < 4; ++fn) {
        int cl = wc * 64 + fn * 16 + (lane & 15);
        float bv = (bias != nullptr) ? bias[bn + cl] : 0.f;
        #pragma unroll
        for (int fm = 0; fm < 4; ++fm) {
            #pragma unroll
            for (int j = 0; j < 4; ++j) {
                int lr = wr * 64 + fm * 16 + (lane >> 4) * 4 + j;
                float v = acc[fm][fn][j] + bv;
                if (MODE == 2) v = geluf(v);
                if (MODE == 4 && zhalf) v = v / (1.f + __expf(-v));
                rs[lr * 128 + cl] = f2bf(v);
            }
        }
    }
    __syncthreads();
    int r = tid >> 1, half = tid & 1;
    u16* dst = Cb + (size_t)(bm + r) * ldc + bn + half * 64;
    const u16* src = rs + r * 128 + half * 64;
    #pragma unroll
    for (int i = 0; i < 8; ++i)
        *(bf8_t*)&dst[i * 8] = *(const bf8_t*)&src[i * 8];
}

// ---------------------------------------------------------------------------
// 3b. narrow x_proj GEMM: xdbl[M,48] = xc @ W[48,512]^T (dbuf)
//     A = bf16 xc plane (row stride XW), W = hi/lo planes.
// ---------------------------------------------------------------------------
__global__ __launch_bounds__(256)
void gemm_xproj(const u16* __restrict__ Axz,           // xzb, row stride XW
                const u16* __restrict__ Wh, const u16* __restrict__ Wl,
                float* __restrict__ C) {               // ldc = 48
    __shared__ u16 sA[2][128 * 32];                    // 16KB
    __shared__ u16 sB[2][2][48 * 32];                  // 12KB
    int tid = threadIdx.x;
    int lane = tid & 63, wid = tid >> 6;
    int bm = blockIdx.x * 128;

    f4_t acc[2][3];
    #pragma unroll
    for (int i = 0; i < 2; ++i)
        #pragma unroll
        for (int j = 0; j < 3; ++j)
            acc[i][j] = (f4_t){0.f, 0.f, 0.f, 0.f};

    int scol = (lane & 3) * 8;

    auto stage = [&](int bi, int k0) {
        #pragma unroll
        for (int qq = 0; qq < 2; ++qq) {
            int row = wid * 32 + qq * 16 + (lane >> 2);
            size_t ga = (size_t)(bm + row) * XW + k0 + scol;
            int off = (wid * 2 + qq) * 1024;
            gload16(Axz + ga, (char*)&sA[bi][0] + off);
        }
        if (tid < 192) {
            int row = tid >> 2;
            int c16 = (tid & 3) * 8;
            size_t gb = (size_t)row * EE + k0 + c16;
            gload16(Wh + gb, (char*)&sB[bi][0][0] + tid * 16);
            gload16(Wl + gb, (char*)&sB[bi][1][0] + tid * 16);
        }
    };
    auto compute = [&](int bi) {
        int arow = wid * 32 + (lane & 15);
        int koff = (lane >> 4) * 8;
        bf8_t ah[2];
        #pragma unroll
        for (int fm = 0; fm < 2; ++fm) {
            int r = arow + fm * 16;
            ah[fm] = *(const bf8_t*)&sA[bi][r * 32 + koff];
        }
        #pragma unroll
        for (int fn = 0; fn < 3; ++fn) {
            int r = fn * 16 + (lane & 15);
            bf8_t bh = *(const bf8_t*)&sB[bi][0][r * 32 + koff];
            bf8_t bl = *(const bf8_t*)&sB[bi][1][r * 32 + koff];
            #pragma unroll
            for (int fm = 0; fm < 2; ++fm) {
                acc[fm][fn] = __builtin_amdgcn_mfma_f32_16x16x32_bf16(ah[fm], bh, acc[fm][fn], 0, 0, 0);
                acc[fm][fn] = __builtin_amdgcn_mfma_f32_16x16x32_bf16(ah[fm], bl, acc[fm][fn], 0, 0, 0);
            }
        }
    };

    stage(0, 0);
    __syncthreads();
    int cur = 0;
    for (int k0 = 0; k0 < EE; k0 += 32) {
        if (k0 + 32 < EE) stage(cur ^ 1, k0 + 32);
        compute(cur);
        __syncthreads();
        cur ^= 1;
    }

    #pragma unroll
    for (int fn = 0; fn < 3; ++fn) {
        int colg = fn * 16 + (lane & 15);
        #pragma unroll
        for (int fm = 0; fm < 2; ++fm) {
            #pragma unroll
            for (int j = 0; j < 4; ++j) {
                int rowg = bm + wid * 32 + fm * 16 + (lane >> 4) * 4 + j;
                C[(size_t)rowg * 48 + colg] = acc[fm][fn][j];
            }
        }
    }
}

// ---------------------------------------------------------------------------
// 4a. conv halo snapshot (reads bf16 xc, stores fp32 halo)
// ---------------------------------------------------------------------------
__global__ __launch_bounds__(256)
void conv_halo_kernel(const u16* __restrict__ xzb, float* __restrict__ halo) {
    int bid = blockIdx.x;
    int ehalf = bid & 1, bc = bid >> 1;
    int c = bc % NC, b = bc / NC;
    int e = ehalf * 256 + threadIdx.x;
    int t0 = c * CL;
    const u16* xp = xzb + (size_t)b * TT * XW + e;
    float* hp = halo + (((size_t)b * NC + c) * 3) * EE + e;
    #pragma unroll
    for (int k = 0; k < 3; ++k) {
        int t = t0 - 3 + k;
        hp[(size_t)k * EE] = (t >= 0) ? bf2f(xp[(size_t)t * XW]) : 0.f;
    }
}

// ---------------------------------------------------------------------------
// 4b. chunked causal depthwise conv (K=4) + bias + SiLU, in place, bf16
// ---------------------------------------------------------------------------
__global__ __launch_bounds__(256)
void conv_chunk_kernel(u16* __restrict__ xzb, const float* __restrict__ halo,
                       const float* __restrict__ conv_w,
                       const float* __restrict__ conv_b, int layer) {
    int bid = blockIdx.x;
    int ehalf = bid & 1, bc = bid >> 1;
    int c = bc % NC, b = bc / NC;
    int e = ehalf * 256 + threadIdx.x;
    int t0 = c * CL;
    const float* w = conv_w + ((size_t)layer * EE + e) * KCONV;
    float w0 = w[0], w1 = w[1], w2 = w[2], w3 = w[3];
    float bias = conv_b[layer * EE + e];
    const float* hp = halo + (((size_t)b * NC + c) * 3) * EE + e;
    float h0 = hp[0], h1 = hp[(size_t)EE], h2 = hp[(size_t)2 * EE];
    u16* p = xzb + ((size_t)b * TT + t0) * XW + e;

    float c0 = bf2f(p[0]);
    float c1 = bf2f(p[(size_t)XW]);
    for (int tg = 0; tg < CL; tg += 2) {
        float n0, n1;
        if (tg + 2 < CL) {
            n0 = bf2f(p[(size_t)(tg + 2) * XW]);
            n1 = bf2f(p[(size_t)(tg + 3) * XW]);
        }
        float v0 = fmaf(w0, h0, fmaf(w1, h1, fmaf(w2, h2, fmaf(w3, c0, bias))));
        float v1 = fmaf(w0, h1, fmaf(w1, h2, fmaf(w2, c0, fmaf(w3, c1, bias))));
        p[(size_t)(tg + 0) * XW] = f2bf(v0 / (1.f + __expf(-v0)));
        p[(size_t)(tg + 1) * XW] = f2bf(v1 / (1.f + __expf(-v1)));
        h0 = h2; h1 = c0; h2 = c1;
        if (tg + 2 < CL) { c0 = n0; c1 = n1; }
    }
}

// ---------------------------------------------------------------------------
// 5. chunked selective scan (NC=6, CL=50), TWO e-values per thread
//    (e = 2*tid, 2*tid+1).  z slots now hold PRE-SILU'd values (in_proj MODE 4)
//    so EMIT does a single multiply.
// ---------------------------------------------------------------------------
__device__ __forceinline__ bool chain_check(const float* __restrict__ alp,
                                            float& A0l2e) {
    float a0 = -expf(alp[0]);
    bool ch = true;
    #pragma unroll
    for (int n = 1; n < 16; ++n) {
        float an = -expf(alp[n]);
        ch = ch && (fabsf(an - (n + 1) * a0) <= 1e-3f * (n + 1) * fabsf(a0));
    }
    A0l2e = a0 * LOG2E;
    return ch;
}

template <bool CHAIN, bool EMIT>
__device__ __forceinline__ void scan2_body(
        const float* __restrict__ rowp,
        u16* __restrict__ xp,              // base + e0 (even, 4B aligned)
        const float dw[2][16], const float db[2],
        const float A0[2], const float (*arl)[16],
        const float Dv[2], float2 (*s2)[8], float* dsum) {
    unsigned xcur = *(const unsigned*)xp;
    unsigned zcur = 0;
    if (EMIT) zcur = *(const unsigned*)(xp + EE);
    for (int t = 0; t < CL; ++t) {
        unsigned xnxt = 0, znxt = 0;
        if (t + 1 < CL) {
            xnxt = *(const unsigned*)(xp + (size_t)(t + 1) * XW);
            if (EMIT) znxt = *(const unsigned*)(xp + (size_t)(t + 1) * XW + EE);
        }
        const float* row = rowp + (size_t)t * 48;
        float2 rw[8], Bv[8], Cv[8];
        #pragma unroll
        for (int j = 0; j < 8; ++j) {
            rw[j] = *(const float2*)(row + 2 * j);
            Bv[j] = *(const float2*)(row + 16 + 2 * j);
            if (EMIT) Cv[j] = *(const float2*)(row + 32 + 2 * j);
        }
        unsigned uout = 0;
        #pragma unroll
        for (int v = 0; v < 2; ++v) {
            float r0 = db[v], r1 = 0.f;
            #pragma unroll
            for (int j = 0; j < 8; ++j) {
                r0 = fmaf(rw[j].x, dw[v][2 * j], r0);
                r1 = fmaf(rw[j].y, dw[v][2 * j + 1], r1);
            }
            float rr = r0 + r1;
            float qv = exp2f(-fabsf(rr) * LOG2E);
            float dt = fmaxf(rr, 0.f) + LN2 * __log2f(1.f + qv);
            if (!EMIT) dsum[v] += dt;
            float xv = bf2f((u16)(v == 0 ? (xcur & 0xffffu) : (xcur >> 16)));
            float dx = dt * xv;
            float2 P[8];
            if (CHAIN) {
                float w1 = exp2f(dt * A0[v]);
                float w2 = w1 * w1;
                float2 w2v = make_float2(w2, w2);
                P[0] = make_float2(w1, w2);
                #pragma unroll
                for (int k = 1; k < 8; ++k) P[k] = P[k - 1] * w2v;
            } else {
                #pragma unroll
                for (int k = 0; k < 8; ++k)
                    P[k] = make_float2(exp2f(dt * arl[v][2 * k]),
                                       exp2f(dt * arl[v][2 * k + 1]));
            }
            float2 dx2 = make_float2(dx, dx);
            float2 qa = make_float2(0.f, 0.f), qb = make_float2(0.f, 0.f);
            #pragma unroll
            for (int k = 0; k < 8; ++k) {
                s2[v][k] = s2[v][k] * P[k] + dx2 * Bv[k];
                if (EMIT) {
                    if (k & 1) qb += s2[v][k] * Cv[k];
                    else       qa += s2[v][k] * Cv[k];
                }
            }
            if (EMIT) {
                float2 qs = qa + qb;
                float y = (qs.x + qs.y) + xv * Dv[v];
                float sz = bf2f((u16)(v == 0 ? (zcur & 0xffffu) : (zcur >> 16)));
                float u = y * sz;                   // z pre-silu'd in in_proj
                uout |= (unsigned)f2bf(u) << (16 * v);
            }
        }
        if (EMIT) *(unsigned*)(xp + (size_t)t * XW) = uout;
        xcur = xnxt; zcur = znxt;
    }
}

__device__ __forceinline__ void load_scan2_params(
        const float* dt_w, const float* dt_b, const float* A_log,
        int layer, int e0, float dw[2][16], float db[2], float A0[2],
        bool& chain) {
    chain = true;
    #pragma unroll
    for (int v = 0; v < 2; ++v) {
        int e = e0 + v;
        #pragma unroll
        for (int i = 0; i < 16; i += 4)
            *(float4*)&dw[v][i] = *(const float4*)(dt_w + ((size_t)layer * EE + e) * RR + i);
        db[v] = dt_b[layer * EE + e];
        float a0;
        bool c = chain_check(A_log + ((size_t)layer * EE + e) * NSTATE, a0);
        A0[v] = a0;
        chain = chain && c;
    }
}

__device__ __forceinline__ void load_arl2(const float* A_log, int layer, int e0,
                                          float arl[2][16]) {
    #pragma unroll
    for (int v = 0; v < 2; ++v) {
        const float* alp = A_log + ((size_t)layer * EE + e0 + v) * NSTATE;
        #pragma unroll
        for (int i = 0; i < 16; i += 4) {
            float4 x4 = *(const float4*)(alp + i);
            arl[v][i + 0] = -expf(x4.x) * LOG2E;
            arl[v][i + 1] = -expf(x4.y) * LOG2E;
            arl[v][i + 2] = -expf(x4.z) * LOG2E;
            arl[v][i + 3] = -expf(x4.w) * LOG2E;
        }
    }
}

__global__ __launch_bounds__(256, 1)
void scan_p1(const float* __restrict__ xdbl, u16* __restrict__ xzb,
             const float* __restrict__ dt_w, const float* __restrict__ dt_b,
             const float* __restrict__ A_log,
             float* __restrict__ SF, float* __restrict__ DS, int layer) {
    int bid = blockIdx.x;
    int c = bid % NC, b = bid / NC;
    int e0 = threadIdx.x * 2;
    int t0 = c * CL;
    float dw[2][16], db[2], A0[2];
    bool chain;
    load_scan2_params(dt_w, dt_b, A_log, layer, e0, dw, db, A0, chain);

    const float* rowp = xdbl + ((size_t)b * TT + t0) * 48;
    u16* xp = xzb + ((size_t)b * TT + t0) * XW + e0;
    float2 s2[2][8];
    #pragma unroll
    for (int v = 0; v < 2; ++v)
        #pragma unroll
        for (int k = 0; k < 8; ++k) s2[v][k] = make_float2(0.f, 0.f);
    float dsum[2] = {0.f, 0.f};
    float Dv[2] = {0.f, 0.f};
    if (chain) {
        scan2_body<true, false>(rowp, xp, dw, db, A0, nullptr, Dv, s2, dsum);
    } else {
        float arl[2][16];
        load_arl2(A_log, layer, e0, arl);
        scan2_body<false, false>(rowp, xp, dw, db, A0, arl, Dv, s2, dsum);
    }
    #pragma unroll
    for (int v = 0; v < 2; ++v) {
        size_t sbase = (((size_t)b * EE + e0 + v) * NC + c) * 16;
        #pragma unroll
        for (int k = 0; k < 8; ++k) *(float2*)(SF + sbase + 2 * k) = s2[v][k];
        DS[((size_t)b * EE + e0 + v) * NC + c] = dsum[v];
    }
}

__global__ __launch_bounds__(256)
void scan_p2(const float* __restrict__ A_log,
             float* __restrict__ SF, const float* __restrict__ DS, int layer) {
    int g = blockIdx.x * 256 + threadIdx.x;       // 0..B*E-1
    int e = g & (EE - 1), b = g >> 9;
    const float* alp = A_log + ((size_t)layer * EE + e) * NSTATE;
    float arl2e[16];
    #pragma unroll
    for (int i = 0; i < 16; i += 4) {
        float4 v = *(const float4*)(alp + i);
        arl2e[i + 0] = -expf(v.x) * LOG2E; arl2e[i + 1] = -expf(v.y) * LOG2E;
        arl2e[i + 2] = -expf(v.z) * LOG2E; arl2e[i + 3] = -expf(v.w) * LOG2E;
    }
    float s[16];
    #pragma unroll
    for (int n = 0; n < 16; ++n) s[n] = 0.f;
    size_t base = ((size_t)b * EE + e) * NC;
    for (int c = 0; c < NC; ++c) {
        float ds = DS[base + c];
        alignas(16) float f[16];
        #pragma unroll
        for (int i = 0; i < 16; i += 4) *(float4*)&f[i] = *(const float4*)(SF + (base + c) * 16 + i);
        #pragma unroll
        for (int i = 0; i < 16; i += 4) *(float4*)(SF + (base + c) * 16 + i) = *(float4*)&s[i];
        #pragma unroll
        for (int n = 0; n < 16; ++n) s[n] = fmaf(s[n], exp2f(ds * arl2e[n]), f[n]);
    }
}

__global__ __launch_bounds__(256, 1)
void scan_p3(const float* __restrict__ xdbl, u16* __restrict__ xzb,
             const float* __restrict__ dt_w, const float* __restrict__ dt_b,
             const float* __restrict__ A_log, const float* __restrict__ Dp,
             const float* __restrict__ SF, int layer) {
    int bid = blockIdx.x;
    int c = bid % NC, b = bid / NC;
    int e0 = threadIdx.x * 2;
    int t0 = c * CL;
    float dw[2][16], db[2], A0[2];
    bool chain;
    load_scan2_params(dt_w, dt_b, A_log, layer, e0, dw, db, A0, chain);
    float Dv[2];
    Dv[0] = Dp[layer * EE + e0];
    Dv[1] = Dp[layer * EE + e0 + 1];

    const float* rowp = xdbl + ((size_t)b * TT + t0) * 48;
    u16* xp = xzb + ((size_t)b * TT + t0) * XW + e0;
    float2 s2[2][8];
    #pragma unroll
    for (int v = 0; v < 2; ++v) {
        size_t sbase = (((size_t)b * EE + e0 + v) * NC + c) * 16;
        #pragma unroll
        for (int k = 0; k < 8; ++k) s2[v][k] = *(const float2*)(SF + sbase + 2 * k);
    }
    float dsum[2] = {0.f, 0.f};
    if (chain) {
        scan2_body<true, true>(rowp, xp, dw, db, A0, nullptr, Dv, s2, dsum);
    } else {
        float arl[2][16];
        load_arl2(A_log, layer, e0, arl);
        scan2_body<false, true>(rowp, xp, dw, db, A0, arl, Dv, s2, dsum);
    }
}

// ---------------------------------------------------------------------------
// 6. final gather
// ---------------------------------------------------------------------------
__global__ __launch_bounds__(256)
void gather_out_kernel(const u16* __restrict__ hh, const u16* __restrict__ hl,
                       const int* __restrict__ seq_len,
                       float* __restrict__ out) {
    int b = blockIdx.x;
    int sl = seq_len[b];
    int tl = sl + sl / 2;
    int idx = tl - 1;
    if (idx < 0) idx = 0;
    if (idx > TT - 1) idx = TT - 1;
    size_t src = ((size_t)b * TT + idx) * HH + threadIdx.x;
    out[(size_t)b * HH + threadIdx.x] = bf2f(hh[src]) + bf2f(hl[src]);
}

// ---------------------------------------------------------------------------
// launch
// ---------------------------------------------------------------------------
extern "C" void kernel_launch(void* const* d_in, const int* in_sizes, int n_in,
                              void* d_out, int out_size, void* d_ws, size_t ws_size,
                              hipStream_t stream) {
    const int*   item_seq  = (const int*)  d_in[0];
    const int*   seq_len   = (const int*)  d_in[1];
    const float* item_emb  = (const float*)d_in[2];
    const float* ln_w      = (const float*)d_in[3];
    const float* ln_b      = (const float*)d_in[4];
    const float* in_proj_w = (const float*)d_in[5];
    const float* conv_w    = (const float*)d_in[6];
    const float* conv_b    = (const float*)d_in[7];
    const float* x_proj_w  = (const float*)d_in[8];
    const float* dt_w      = (const float*)d_in[9];
    const float* dt_b      = (const float*)d_in[10];
    const float* A_log     = (const float*)d_in[11];
    const float* Dp        = (const float*)d_in[12];
    const float* out_w     = (const float*)d_in[13];
    const float* mn_w      = (const float*)d_in[14];
    const float* mn_b      = (const float*)d_in[15];
    const float* fc1_w     = (const float*)d_in[16];
    const float* fc1_b     = (const float*)d_in[17];
    const float* fc2_w     = (const float*)d_in[18];
    const float* fc2_b     = (const float*)d_in[19];
    const float* fn_w      = (const float*)d_in[20];
    const float* fn_b      = (const float*)d_in[21];

    // ---- workspace layout (~360 MB, well under proven 486 MB) ----
    u16*   xzb  = (u16*)d_ws;                         // 157,286,400 B
    u16*   hh   = xzb + (size_t)MTOK * XW;            //  39,321,600 B
    u16*   hl   = hh + (size_t)MTOK * HH;             //  39,321,600 B
    u16*   tmpb = hl + (size_t)MTOK * HH;             //  39,321,600 B
    float* xdbl = (float*)(tmpb + (size_t)MTOK * HH); //  14,745,600 B
    float* SF   = xdbl + (size_t)MTOK * 48;           //  50,331,648 B (B*E*NC*16)
    float* DS   = SF + (size_t)BB * EE * NC * 16;     //   3,145,728 B
    float* halo = DS + (size_t)BB * EE * NC;          //   9,437,184 B (B*NC*3*E)
    u16*   pw   = (u16*)(halo + (size_t)BB * NC * 3 * EE); // 7,536,640 B planes
    u16* inH  = pw;                 u16* inL  = inH  + 524288;
    u16* xpH  = inL  + 524288;      u16* xpL  = xpH  + 49152;
    u16* outH = xpL  + 49152;       u16* outL = outH + 262144;
    u16* f1H  = outL + 262144;      u16* f1L  = f1H  + 524288;
    u16* f2H  = f1L  + 524288;      u16* f2L  = f2H  + 524288;
    // fc1 bf16 output plane aliases xzb (xc/z/u dead by then):
    u16* ffb = xzb;

    // ---- split ALL weights once ----
    split_kernel<<<524288 / 256, 256, 0, stream>>>(in_proj_w, inH, inL, 524288);
    split_kernel<<<49152 / 256, 256, 0, stream>>>(x_proj_w, xpH, xpL, 49152);
    split_kernel<<<262144 / 256, 256, 0, stream>>>(out_w, outH, outL, 262144);
    split_kernel<<<524288 / 256, 256, 0, stream>>>(fc1_w, f1H, f1L, 524288);
    split_kernel<<<524288 / 256, 256, 0, stream>>>(fc2_w, f2H, f2L, 524288);

    embed_ln_kernel<<<MTOK / 4, 256, 0, stream>>>(item_seq, item_emb, ln_w, ln_b, hh, hl);

    const int gconv = BB * NC * 2;                    // 3072 blocks
    const int gscan = BB * NC;                        // 1536 blocks (2 e/thread)

    for (int l = 0; l < NLAYER; ++l) {
        // in_proj: xzb = bf16(h @ in_proj_w[l]^T), silu on z half (MODE 4)
        {
            dim3 grid((2 * EE) / 128, MTOK / 128);
            gemm_mfma<4><<<grid, 256, 0, stream>>>(
                hh, HH,
                inH + (size_t)l * 262144,
                nullptr, xzb, MTOK, 2 * EE, HH, XW);
        }
        // chunked conv (bf16 in place)
        conv_halo_kernel<<<gconv, 256, 0, stream>>>(xzb, halo);
        conv_chunk_kernel<<<gconv, 256, 0, stream>>>(xzb, halo, conv_w, conv_b, l);
        // x_proj (A = bf16 xc plane, W hi/lo)
        gemm_xproj<<<MTOK / 128, 256, 0, stream>>>(
            xzb, xpH + (size_t)l * 24576, xpL + (size_t)l * 24576, xdbl);
        // chunked selective scan (2 e/thread); p3 writes u bf16 over xc slots
        scan_p1<<<gscan, 256, 0, stream>>>(xdbl, xzb, dt_w, dt_b, A_log, SF, DS, l);
        scan_p2<<<(BB * EE) / 256, 256, 0, stream>>>(A_log, SF, DS, l);
        scan_p3<<<gscan, 256, 0, stream>>>(xdbl, xzb, dt_w, dt_b, A_log, Dp, SF, l);
        // out proj: tmpb = bf16(u @ out_w[l]^T)   (M x 256, K=512), 1-term
        {
            dim3 grid(HH / 128, MTOK / 128);
            gemm_mfma<3><<<grid, 256, 0, stream>>>(
                xzb, XW,
                outH + (size_t)l * 131072,
                nullptr, tmpb, MTOK, HH, EE, HH);
        }
        add_ln_kernel<<<MTOK / 4, 256, 0, stream>>>(tmpb, hh, hl, mn_w + l * HH, mn_b + l * HH);
        // fc1 + GELU -> ffb bf16 plane (alias xzb)  (M x 1024, K=256), 1-term
        {
            dim3 grid((4 * HH) / 128, MTOK / 128);
            gemm_mfma<2><<<grid, 256, 0, stream>>>(
                hh, HH,
                f1H + (size_t)l * 262144,
                fc1_b + (size_t)l * 4 * HH,
                ffb, MTOK, 4 * HH, HH, XW);
        }
        // fc2: tmpb = bf16(ffb @ fc2_w^T + b)   (M x 256, K=1024), 1-term
        {
            dim3 grid(HH / 128, MTOK / 128);
            gemm_mfma<3><<<grid, 256, 0, stream>>>(
                ffb, XW,
                f2H + (size_t)l * 262144,
                fc2_b + (size_t)l * HH,
                tmpb, MTOK, HH, 4 * HH, HH);
        }
        add_ln_kernel<<<MTOK / 4, 256, 0, stream>>>(tmpb, hh, hl, fn_w + l * HH, fn_b + l * HH);
    }

    gather_out_kernel<<<BB, 256, 0, stream>>>(hh, hl, seq_len, (float*)d_out);
}